// Round 2
// baseline (1812.983 us; speedup 1.0000x reference)
//
#include <hip/hip_runtime.h>

// NRI decoder, fp32 baseline with factored layer-1 projections.
// B=8, N=48, T-1=9 steps, D=4, H=256, edge types 1..3, E=2256 (receiver-major).
//
// Per step t:
//   proj_kernel : PA[k][node][f'] = hidden_t[node]@W1_top[k] + b1[k],
//                 PS[k][node][f'] = hidden_t[node]@W1_bot[k]      (6 x [384,256]@[256,256])
//   edge_kernel : per (b, recv n, h-half): m1[e][f']=tanh(PA[recv]+PS[send]),
//                 msg=tanh(m1@W2[k]+b2[k]); agg[b,n,h]=sum_e sum_k rtyp*msg /12
//   gru_kernel  : GRU update -> hidden_{t+1} (stored per t for pred)
// Final: pred_kernel: batched 2x relu MLP + residual over all 3456 (t,node) rows.

#define H_ 256
#define N_ 48
#define B_ 8
#define NODES 384     // B_*N_
#define TS 9          // T-1

__device__ __forceinline__ float fast_tanh(float x) {
  // tanh(x) = 1 - 2/(1+exp(2x)); robust at +-inf, ~1e-7 rel err
  float e = __expf(2.0f * x);
  return 1.0f - 2.0f * __builtin_amdgcn_rcpf(1.0f + e);
}
__device__ __forceinline__ float fast_sigmoid(float x) {
  float e = __expf(-x);
  return __builtin_amdgcn_rcpf(1.0f + e);
}

// ---------------- proj: PA/PS node projections -----------------------------
// grid: 48 node-tiles * 6 mats = 288 blocks, 256 threads
__global__ __launch_bounds__(256) void proj_kernel(
    const float* __restrict__ hidden, const float* __restrict__ w1,
    const float* __restrict__ b1, float* __restrict__ PA, float* __restrict__ PS) {
  const int mat  = blockIdx.x % 6;
  const int tile = blockIdx.x / 6;
  const int k = mat >> 1, part = mat & 1;
  const int node0 = tile * 8;
  __shared__ float hl[256][12];   // [f][nd], pad 12 for float4 alignment
  for (int i = threadIdx.x; i < 8 * 256; i += 256) {
    int nd = i >> 8, f = i & 255;
    hl[f][nd] = hidden[(node0 + nd) * H_ + f];
  }
  __syncthreads();
  const int h = threadIdx.x;
  const float* W = w1 + ((size_t)((k + 1) * 512 + part * 256)) * H_ + h;
  float acc[8] = {0, 0, 0, 0, 0, 0, 0, 0};
  #pragma unroll 4
  for (int f = 0; f < 256; ++f) {
    float w = W[f * H_];
    const float4 a0 = *(const float4*)&hl[f][0];
    const float4 a1 = *(const float4*)&hl[f][4];
    acc[0] = fmaf(a0.x, w, acc[0]); acc[1] = fmaf(a0.y, w, acc[1]);
    acc[2] = fmaf(a0.z, w, acc[2]); acc[3] = fmaf(a0.w, w, acc[3]);
    acc[4] = fmaf(a1.x, w, acc[4]); acc[5] = fmaf(a1.y, w, acc[5]);
    acc[6] = fmaf(a1.z, w, acc[6]); acc[7] = fmaf(a1.w, w, acc[7]);
  }
  float bias = part ? 0.0f : b1[(k + 1) * H_ + h];
  float* dst = (part ? PS : PA) + k * (NODES * H_) + node0 * H_ + h;
  #pragma unroll
  for (int nd = 0; nd < 8; ++nd) dst[nd * H_] = acc[nd] + bias;
}

// ---------------- edge: layer2 GEMM + weighting + aggregate ----------------
// grid: (48, 8, 2), 256 threads. Block = one receiver node, one 128-h half.
__global__ __launch_bounds__(256) void edge_kernel(
    const float* __restrict__ PA, const float* __restrict__ PS,
    const float* __restrict__ rel_type, const float* __restrict__ w2,
    const float* __restrict__ b2, float* __restrict__ agg) {
  const int n = blockIdx.x;
  const int b = blockIdx.y;
  const int h0 = blockIdx.z * 128;
  const int tid = threadIdx.x;
  const int node = b * N_ + n;

  __shared__ float a_l[3][256];     // PA rows for this receiver
  __shared__ float m1t[32][49];     // [fi][e] transposed m1 chunk
  __shared__ float w_l[32][132];    // W2 chunk [fi][hh]
  __shared__ float rt_l[3][48];     // edge-type weights
  __shared__ float b2_l[3][128];
  __shared__ float red[16][128];    // eg-reduction

  for (int i = tid; i < 3 * 256; i += 256) {
    int k = i >> 8, f = i & 255;
    a_l[k][f] = PA[k * (NODES * H_) + node * H_ + f];
  }
  for (int i = tid; i < 3 * 128; i += 256) {
    int k = i >> 7, hh = i & 127;
    b2_l[k][hh] = b2[(k + 1) * H_ + h0 + hh];
  }
  for (int i = tid; i < 3 * 48; i += 256) {
    int k = i / 48, e = i % 48;
    rt_l[k][e] = (e < 47) ? rel_type[(size_t)(b * 2256 + n * 47 + e) * 4 + (k + 1)] : 0.0f;
  }
  __syncthreads();

  const int eg = tid >> 4;   // 0..15 -> edges {eg, eg+16, eg+32}
  const int hg = tid & 15;   // 0..15 -> h = h0 + hg*8 .. +7
  float agga[8] = {0, 0, 0, 0, 0, 0, 0, 0};

  for (int k = 0; k < 3; ++k) {
    float acc0[8] = {0,0,0,0,0,0,0,0};
    float acc1[8] = {0,0,0,0,0,0,0,0};
    float acc2[8] = {0,0,0,0,0,0,0,0};
    const float* W2k = w2 + (size_t)(k + 1) * H_ * H_;
    const float* PSk = PS + k * (NODES * H_) + b * N_ * H_;
    for (int fc = 0; fc < 8; ++fc) {
      // stage m1 chunk (transposed); e==47 is padding -> 0
      for (int i = tid; i < 48 * 32; i += 256) {
        int e = i >> 5, fi = i & 31;
        float v = 0.0f;
        if (e < 47) {
          int s = e + (e >= n);
          v = fast_tanh(a_l[k][fc * 32 + fi] + PSk[s * H_ + fc * 32 + fi]);
        }
        m1t[fi][e] = v;
      }
      // stage W2 chunk
      for (int i = tid; i < 32 * 128; i += 256) {
        int fi = i >> 7, hh = i & 127;
        w_l[fi][hh] = W2k[(size_t)(fc * 32 + fi) * H_ + h0 + hh];
      }
      __syncthreads();
      #pragma unroll 8
      for (int fi = 0; fi < 32; ++fi) {
        float m0  = m1t[fi][eg];
        float m1v = m1t[fi][eg + 16];
        float m2v = m1t[fi][eg + 32];
        const float4 wa = *(const float4*)&w_l[fi][hg * 8];
        const float4 wb = *(const float4*)&w_l[fi][hg * 8 + 4];
        float wv[8] = {wa.x, wa.y, wa.z, wa.w, wb.x, wb.y, wb.z, wb.w};
        #pragma unroll
        for (int j = 0; j < 8; ++j) {
          acc0[j] = fmaf(m0,  wv[j], acc0[j]);
          acc1[j] = fmaf(m1v, wv[j], acc1[j]);
          acc2[j] = fmaf(m2v, wv[j], acc2[j]);
        }
      }
      __syncthreads();
    }
    // finish type k: bias, tanh, edge-type weight, accumulate
    float r0 = rt_l[k][eg], r1 = rt_l[k][eg + 16], r2 = rt_l[k][eg + 32];
    #pragma unroll
    for (int j = 0; j < 8; ++j) {
      float bb = b2_l[k][hg * 8 + j];
      agga[j] = fmaf(r0, fast_tanh(acc0[j] + bb), agga[j]);
      agga[j] = fmaf(r1, fast_tanh(acc1[j] + bb), agga[j]);
      agga[j] = fmaf(r2, fast_tanh(acc2[j] + bb), agga[j]);
    }
  }
  __syncthreads();
  *(float4*)&red[eg][hg * 8]     = make_float4(agga[0], agga[1], agga[2], agga[3]);
  *(float4*)&red[eg][hg * 8 + 4] = make_float4(agga[4], agga[5], agga[6], agga[7]);
  __syncthreads();
  if (tid < 128) {
    float s = 0.0f;
    #pragma unroll
    for (int p = 0; p < 16; ++p) s += red[p][tid];
    agg[node * H_ + h0 + tid] = s * (1.0f / 12.0f);
  }
}

// ---------------- gru: hidden update ---------------------------------------
// grid: 96 node-tiles * 2 h-halves = 192 blocks, 256 threads
__global__ __launch_bounds__(256) void gru_kernel(
    const float* __restrict__ hprev, const float* __restrict__ agg,
    const float* __restrict__ data,
    const float* __restrict__ wr, const float* __restrict__ wi, const float* __restrict__ wn,
    const float* __restrict__ xrw, const float* __restrict__ xrb,
    const float* __restrict__ xiw, const float* __restrict__ xib,
    const float* __restrict__ xnw, const float* __restrict__ xnb,
    float* __restrict__ hout, int t) {
  const int node0 = (blockIdx.x >> 1) * 4;
  const int half  = blockIdx.x & 1;
  __shared__ float al[256][6];   // [f][nd]
  for (int i = threadIdx.x; i < 4 * 256; i += 256) {
    int nd = i >> 8, f = i & 255;
    al[f][nd] = agg[(node0 + nd) * H_ + f];
  }
  __syncthreads();
  const int hh = threadIdx.x & 127;
  const int h = half * 128 + hh;
  const int np = (threadIdx.x >> 7) * 2;   // 0 or 2
  float ar[2] = {0, 0}, ai[2] = {0, 0}, an[2] = {0, 0};
  const float* pr = wr + h;
  const float* pi = wi + h;
  const float* pn = wn + h;
  #pragma unroll 4
  for (int f = 0; f < 256; ++f) {
    float wrv = pr[f * H_], wiv = pi[f * H_], wnv = pn[f * H_];
    const float2 a = *(const float2*)&al[f][np];
    ar[0] = fmaf(a.x, wrv, ar[0]); ar[1] = fmaf(a.y, wrv, ar[1]);
    ai[0] = fmaf(a.x, wiv, ai[0]); ai[1] = fmaf(a.y, wiv, ai[1]);
    an[0] = fmaf(a.x, wnv, an[0]); an[1] = fmaf(a.y, wnv, an[1]);
  }
  #pragma unroll
  for (int u = 0; u < 2; ++u) {
    int node = node0 + np + u;
    const float* ins = data + (size_t)(node * 10 + t) * 4;   // data[b][n][t][:]
    float xr = xrb[h], xi = xib[h], xn = xnb[h];
    #pragma unroll
    for (int dd = 0; dd < 4; ++dd) {
      float iv = ins[dd];
      xr = fmaf(iv, xrw[dd * H_ + h], xr);
      xi = fmaf(iv, xiw[dd * H_ + h], xi);
      xn = fmaf(iv, xnw[dd * H_ + h], xn);
    }
    float r  = fast_sigmoid(xr + ar[u]);
    float ii = fast_sigmoid(xi + ai[u]);
    float ng = fast_tanh(xn + r * an[u]);
    float hp = hprev[node * H_ + h];
    hout[node * H_ + h] = (1.0f - ii) * ng + ii * hp;
  }
}

// ---------------- pred: batched output MLP + residual ----------------------
// rows = t*384 + node, 3456 rows; 16 rows/block -> 216 blocks, 256 threads
__global__ __launch_bounds__(256) void pred_kernel(
    const float* __restrict__ h_all, const float* __restrict__ data,
    const float* __restrict__ o1w, const float* __restrict__ o1b,
    const float* __restrict__ o2w, const float* __restrict__ o2b,
    const float* __restrict__ o3w, const float* __restrict__ o3b,
    float* __restrict__ out) {
  const int row0 = blockIdx.x * 16;
  const int tid = threadIdx.x;
  __shared__ float hlt[256][20];
  __shared__ float p1t[256][20];
  __shared__ float p2t[256][20];
  __shared__ float red2[16][16][4];
  for (int i = tid; i < 16 * 256; i += 256) {
    int r = i >> 8, f = i & 255;
    int row = row0 + r, t = row / NODES, nodeI = row % NODES;
    hlt[f][r] = h_all[(size_t)(t + 1) * NODES * H_ + nodeI * H_ + f];
  }
  __syncthreads();
  const int h = tid;
  float acc[16];
  #pragma unroll
  for (int r = 0; r < 16; ++r) acc[r] = 0.0f;
  #pragma unroll 2
  for (int f = 0; f < 256; ++f) {
    float w = o1w[f * H_ + h];
    const float4 g0 = *(const float4*)&hlt[f][0];
    const float4 g1 = *(const float4*)&hlt[f][4];
    const float4 g2 = *(const float4*)&hlt[f][8];
    const float4 g3 = *(const float4*)&hlt[f][12];
    float gv[16] = {g0.x,g0.y,g0.z,g0.w, g1.x,g1.y,g1.z,g1.w,
                    g2.x,g2.y,g2.z,g2.w, g3.x,g3.y,g3.z,g3.w};
    #pragma unroll
    for (int r = 0; r < 16; ++r) acc[r] = fmaf(gv[r], w, acc[r]);
  }
  {
    float bv = o1b[h];
    #pragma unroll
    for (int r = 0; r < 16; ++r) p1t[h][r] = fmaxf(acc[r] + bv, 0.0f);
  }
  __syncthreads();
  #pragma unroll
  for (int r = 0; r < 16; ++r) acc[r] = 0.0f;
  #pragma unroll 2
  for (int f = 0; f < 256; ++f) {
    float w = o2w[f * H_ + h];
    const float4 g0 = *(const float4*)&p1t[f][0];
    const float4 g1 = *(const float4*)&p1t[f][4];
    const float4 g2 = *(const float4*)&p1t[f][8];
    const float4 g3 = *(const float4*)&p1t[f][12];
    float gv[16] = {g0.x,g0.y,g0.z,g0.w, g1.x,g1.y,g1.z,g1.w,
                    g2.x,g2.y,g2.z,g2.w, g3.x,g3.y,g3.z,g3.w};
    #pragma unroll
    for (int r = 0; r < 16; ++r) acc[r] = fmaf(gv[r], w, acc[r]);
  }
  {
    float bv = o2b[h];
    #pragma unroll
    for (int r = 0; r < 16; ++r) p2t[h][r] = fmaxf(acc[r] + bv, 0.0f);
  }
  __syncthreads();
  {
    int r = tid >> 4, p = tid & 15;
    float s0 = 0, s1 = 0, s2 = 0, s3 = 0;
    #pragma unroll
    for (int q = 0; q < 16; ++q) {
      int f = p * 16 + q;
      float v = p2t[f][r];
      s0 = fmaf(v, o3w[f * 4 + 0], s0);
      s1 = fmaf(v, o3w[f * 4 + 1], s1);
      s2 = fmaf(v, o3w[f * 4 + 2], s2);
      s3 = fmaf(v, o3w[f * 4 + 3], s3);
    }
    red2[r][p][0] = s0; red2[r][p][1] = s1; red2[r][p][2] = s2; red2[r][p][3] = s3;
  }
  __syncthreads();
  if (tid < 64) {
    int r = tid >> 2, dd = tid & 3;
    float s = o3b[dd];
    #pragma unroll
    for (int p = 0; p < 16; ++p) s += red2[r][p][dd];
    int row = row0 + r, t = row / NODES, nodeI = row % NODES;
    s += data[(size_t)(nodeI * 10 + t) * 4 + dd];
    out[(size_t)(nodeI * TS + t) * 4 + dd] = s;
  }
}

// ---------------------------------------------------------------------------
extern "C" void kernel_launch(void* const* d_in, const int* in_sizes, int n_in,
                              void* d_out, int out_size, void* d_ws, size_t ws_size,
                              hipStream_t stream) {
  const float* data     = (const float*)d_in[0];
  const float* rel_type = (const float*)d_in[1];
  // d_in[2]=rel_rec, d_in[3]=rel_send: structure hardcoded (receiver-major edge list)
  const float* w1  = (const float*)d_in[4];
  const float* b1  = (const float*)d_in[5];
  const float* w2  = (const float*)d_in[6];
  const float* b2  = (const float*)d_in[7];
  const float* hr  = (const float*)d_in[8];
  const float* hi  = (const float*)d_in[9];
  const float* hn  = (const float*)d_in[10];
  const float* inr_w = (const float*)d_in[11]; const float* inr_b = (const float*)d_in[12];
  const float* ini_w = (const float*)d_in[13]; const float* ini_b = (const float*)d_in[14];
  const float* inn_w = (const float*)d_in[15]; const float* inn_b = (const float*)d_in[16];
  const float* o1w = (const float*)d_in[17]; const float* o1b = (const float*)d_in[18];
  const float* o2w = (const float*)d_in[19]; const float* o2b = (const float*)d_in[20];
  const float* o3w = (const float*)d_in[21]; const float* o3b = (const float*)d_in[22];
  float* out = (float*)d_out;

  float* ws   = (float*)d_ws;
  float* h_all = ws;                        // [10][384][256]
  float* PA    = ws + 10 * NODES * H_;      // [3][384][256]
  float* PS    = PA + 3 * NODES * H_;       // [3][384][256]
  float* agg   = PS + 3 * NODES * H_;       // [384][256]

  // hidden_0 = 0 (ws is poisoned before each launch)
  hipMemsetAsync(h_all, 0, NODES * H_ * sizeof(float), stream);

  for (int t = 0; t < TS; ++t) {
    proj_kernel<<<288, 256, 0, stream>>>(h_all + (size_t)t * NODES * H_, w1, b1, PA, PS);
    edge_kernel<<<dim3(N_, B_, 2), 256, 0, stream>>>(PA, PS, rel_type, w2, b2, agg);
    gru_kernel<<<192, 256, 0, stream>>>(h_all + (size_t)t * NODES * H_, agg, data,
                                        hr, hi, hn,
                                        inr_w, inr_b, ini_w, ini_b, inn_w, inn_b,
                                        h_all + (size_t)(t + 1) * NODES * H_, t);
  }
  pred_kernel<<<216, 256, 0, stream>>>(h_all, data, o1w, o1b, o2w, o2b, o3w, o3b, out);
}

// Round 3
// 1653.708 us; speedup vs baseline: 1.0963x; 1.0963x over previous
//
#include <hip/hip_runtime.h>

// NRI decoder, fp32, factored layer-1 projections.
// B=8, N=48, T-1=9 steps, D=4, H=256, edge types 1..3, E=2256 (receiver-major).
//
// Round 3 changes (edge_kernel):
//  - k moved to grid: (48,8,6) = 2304 blocks; per-k partials agg3[3][384][256],
//    summed inside gru_kernel. Occupancy was grid-capped at 3 blocks/CU.
//  - w_l read slot interleave (slots hg, hg+16): 4-way LDS conflict -> 2-way (free).
//  - register double-buffer staging: next chunk's W2/PS global loads issued
//    before current chunk's FMA loop; tanh + LDS write after the barrier.
//  - red reduction buffer unioned with w_l: LDS 36KB -> 24.4KB (6 blocks/CU).

#define H_ 256
#define N_ 48
#define B_ 8
#define NODES 384     // B_*N_
#define TS 9          // T-1

__device__ __forceinline__ float fast_tanh(float x) {
  float e = __expf(2.0f * x);
  return 1.0f - 2.0f * __builtin_amdgcn_rcpf(1.0f + e);
}
__device__ __forceinline__ float fast_sigmoid(float x) {
  float e = __expf(-x);
  return __builtin_amdgcn_rcpf(1.0f + e);
}

// ---------------- proj: PA/PS node projections -----------------------------
// grid: 48 node-tiles * 6 mats = 288 blocks, 256 threads
__global__ __launch_bounds__(256) void proj_kernel(
    const float* __restrict__ hidden, const float* __restrict__ w1,
    const float* __restrict__ b1, float* __restrict__ PA, float* __restrict__ PS) {
  const int mat  = blockIdx.x % 6;
  const int tile = blockIdx.x / 6;
  const int k = mat >> 1, part = mat & 1;
  const int node0 = tile * 8;
  __shared__ float hl[256][12];
  for (int i = threadIdx.x; i < 8 * 256; i += 256) {
    int nd = i >> 8, f = i & 255;
    hl[f][nd] = hidden[(node0 + nd) * H_ + f];
  }
  __syncthreads();
  const int h = threadIdx.x;
  const float* W = w1 + ((size_t)((k + 1) * 512 + part * 256)) * H_ + h;
  float acc[8] = {0, 0, 0, 0, 0, 0, 0, 0};
  #pragma unroll 4
  for (int f = 0; f < 256; ++f) {
    float w = W[f * H_];
    const float4 a0 = *(const float4*)&hl[f][0];
    const float4 a1 = *(const float4*)&hl[f][4];
    acc[0] = fmaf(a0.x, w, acc[0]); acc[1] = fmaf(a0.y, w, acc[1]);
    acc[2] = fmaf(a0.z, w, acc[2]); acc[3] = fmaf(a0.w, w, acc[3]);
    acc[4] = fmaf(a1.x, w, acc[4]); acc[5] = fmaf(a1.y, w, acc[5]);
    acc[6] = fmaf(a1.z, w, acc[6]); acc[7] = fmaf(a1.w, w, acc[7]);
  }
  float bias = part ? 0.0f : b1[(k + 1) * H_ + h];
  float* dst = (part ? PS : PA) + k * (NODES * H_) + node0 * H_ + h;
  #pragma unroll
  for (int nd = 0; nd < 8; ++nd) dst[nd * H_] = acc[nd] + bias;
}

// ---------------- edge: layer2 GEMM + weighting + aggregate ----------------
// grid: (48, 8, 6) z = k*2 + h-half; 256 threads. One (receiver, k, 128-h).
__global__ __launch_bounds__(256) void edge_kernel(
    const float* __restrict__ PA, const float* __restrict__ PS,
    const float* __restrict__ rel_type, const float* __restrict__ w2,
    const float* __restrict__ b2, float* __restrict__ agg3) {
  const int n = blockIdx.x;
  const int b = blockIdx.y;
  const int k  = blockIdx.z >> 1;
  const int h0 = (blockIdx.z & 1) * 128;
  const int tid = threadIdx.x;
  const int node = b * N_ + n;

  __shared__ float a_l[256];        // PA row for this (receiver, k)
  __shared__ float m1t[32][49];     // [fi][e] transposed m1 chunk
  __shared__ float b2_l[128];
  __shared__ float rt_l[48];
  __shared__ float wred[32 * 128];  // w_l [32][128]; red [16][128] after last use
  float* w_l = wred;
  float* red = wred;

  a_l[tid] = PA[k * (NODES * H_) + node * H_ + tid];
  if (tid < 128) b2_l[tid] = b2[(k + 1) * H_ + h0 + tid];
  if (tid < 48)
    rt_l[tid] = (tid < 47) ? rel_type[(size_t)(b * 2256 + n * 47 + tid) * 4 + (k + 1)] : 0.0f;

  const float* W2k = w2 + (size_t)(k + 1) * H_ * H_ + h0;
  const float* PSk = PS + k * (NODES * H_) + b * N_ * H_;

  // staging index precompute
  const int fi0  = tid & 31;        // f-within-chunk for PS/m1 staging
  const int c4   = tid & 31;        // float4 column for W staging
  const int fiW0 = tid >> 5;        // base W row
  int srow[6];
  #pragma unroll
  for (int j = 0; j < 6; ++j) {
    int e = (tid + 256 * j) >> 5;             // 0..47
    int ee = (e < 47) ? e : 0;                // clamp pad row (value masked later)
    srow[j] = ee + (ee >= n);                 // sender node index
  }

  float4 wreg[4];
  float  psreg[6];

  #define LOAD_CHUNK(FC)                                                         \
    {                                                                            \
      _Pragma("unroll")                                                          \
      for (int j = 0; j < 4; ++j)                                                \
        wreg[j] = *(const float4*)&W2k[(size_t)((FC) * 32 + fiW0 + 8 * j) * H_ + c4 * 4]; \
      _Pragma("unroll")                                                          \
      for (int j = 0; j < 6; ++j)                                                \
        psreg[j] = PSk[srow[j] * H_ + (FC) * 32 + fi0];                          \
    }

  #define WRITE_CHUNK(FC)                                                        \
    {                                                                            \
      _Pragma("unroll")                                                          \
      for (int j = 0; j < 4; ++j)                                                \
        *(float4*)&w_l[(fiW0 + 8 * j) * 128 + c4 * 4] = wreg[j];                 \
      _Pragma("unroll")                                                          \
      for (int j = 0; j < 6; ++j) {                                              \
        int e = (tid + 256 * j) >> 5;                                            \
        float v = (e < 47) ? fast_tanh(a_l[(FC) * 32 + fi0] + psreg[j]) : 0.0f;  \
        m1t[fi0][e] = v;                                                         \
      }                                                                          \
    }

  LOAD_CHUNK(0);
  __syncthreads();        // invariant preloads (a_l) visible
  WRITE_CHUNK(0);
  __syncthreads();

  const int eg = tid >> 4;   // 0..15 -> edges {eg, eg+16, eg+32}
  const int hg = tid & 15;   // h = h0 + hg*4..+3  and  h0+64+hg*4..+3
  float acc0[8] = {0,0,0,0,0,0,0,0};
  float acc1[8] = {0,0,0,0,0,0,0,0};
  float acc2[8] = {0,0,0,0,0,0,0,0};

  for (int fc = 0; fc < 8; ++fc) {
    if (fc < 7) LOAD_CHUNK(fc + 1);     // in-flight across the compute phase
    #pragma unroll 8
    for (int fi = 0; fi < 32; ++fi) {
      float m0  = m1t[fi][eg];
      float m1v = m1t[fi][eg + 16];
      float m2v = m1t[fi][eg + 32];
      const float4 wa = *(const float4*)&w_l[fi * 128 + hg * 4];        // slot hg
      const float4 wb = *(const float4*)&w_l[fi * 128 + 64 + hg * 4];   // slot hg+16
      float wv[8] = {wa.x, wa.y, wa.z, wa.w, wb.x, wb.y, wb.z, wb.w};
      #pragma unroll
      for (int j = 0; j < 8; ++j) {
        acc0[j] = fmaf(m0,  wv[j], acc0[j]);
        acc1[j] = fmaf(m1v, wv[j], acc1[j]);
        acc2[j] = fmaf(m2v, wv[j], acc2[j]);
      }
    }
    __syncthreads();
    if (fc < 7) WRITE_CHUNK(fc + 1);
    __syncthreads();
  }

  // finish: bias, tanh, edge-type weight
  float agga[8];
  float r0 = rt_l[eg], r1 = rt_l[eg + 16], r2 = rt_l[eg + 32];
  #pragma unroll
  for (int j = 0; j < 8; ++j) {
    float bb = (j < 4) ? b2_l[hg * 4 + j] : b2_l[64 + hg * 4 + (j - 4)];
    float s = r0 * fast_tanh(acc0[j] + bb);
    s = fmaf(r1, fast_tanh(acc1[j] + bb), s);
    s = fmaf(r2, fast_tanh(acc2[j] + bb), s);
    agga[j] = s;
  }
  // red overlaps w_l: last w_l read was before the final barrier above
  *(float4*)&red[eg * 128 + hg * 4]      = make_float4(agga[0], agga[1], agga[2], agga[3]);
  *(float4*)&red[eg * 128 + 64 + hg * 4] = make_float4(agga[4], agga[5], agga[6], agga[7]);
  __syncthreads();
  if (tid < 128) {
    float s = 0.0f;
    #pragma unroll
    for (int p = 0; p < 16; ++p) s += red[p * 128 + tid];
    agg3[(size_t)(k * NODES + node) * H_ + h0 + tid] = s * (1.0f / 12.0f);
  }
}

// ---------------- gru: hidden update (sums 3 k-partials) --------------------
__global__ __launch_bounds__(256) void gru_kernel(
    const float* __restrict__ hprev, const float* __restrict__ agg3,
    const float* __restrict__ data,
    const float* __restrict__ wr, const float* __restrict__ wi, const float* __restrict__ wn,
    const float* __restrict__ xrw, const float* __restrict__ xrb,
    const float* __restrict__ xiw, const float* __restrict__ xib,
    const float* __restrict__ xnw, const float* __restrict__ xnb,
    float* __restrict__ hout, int t) {
  const int node0 = (blockIdx.x >> 1) * 4;
  const int half  = blockIdx.x & 1;
  __shared__ float al[256][6];
  for (int i = threadIdx.x; i < 4 * 256; i += 256) {
    int nd = i >> 8, f = i & 255;
    size_t off = (size_t)(node0 + nd) * H_ + f;
    al[f][nd] = agg3[off] + agg3[(size_t)NODES * H_ + off] + agg3[2 * (size_t)NODES * H_ + off];
  }
  __syncthreads();
  const int hh = threadIdx.x & 127;
  const int h = half * 128 + hh;
  const int np = (threadIdx.x >> 7) * 2;
  float ar[2] = {0, 0}, ai[2] = {0, 0}, an[2] = {0, 0};
  const float* pr = wr + h;
  const float* pi = wi + h;
  const float* pn = wn + h;
  #pragma unroll 4
  for (int f = 0; f < 256; ++f) {
    float wrv = pr[f * H_], wiv = pi[f * H_], wnv = pn[f * H_];
    const float2 a = *(const float2*)&al[f][np];
    ar[0] = fmaf(a.x, wrv, ar[0]); ar[1] = fmaf(a.y, wrv, ar[1]);
    ai[0] = fmaf(a.x, wiv, ai[0]); ai[1] = fmaf(a.y, wiv, ai[1]);
    an[0] = fmaf(a.x, wnv, an[0]); an[1] = fmaf(a.y, wnv, an[1]);
  }
  #pragma unroll
  for (int u = 0; u < 2; ++u) {
    int node = node0 + np + u;
    const float* ins = data + (size_t)(node * 10 + t) * 4;
    float xr = xrb[h], xi = xib[h], xn = xnb[h];
    #pragma unroll
    for (int dd = 0; dd < 4; ++dd) {
      float iv = ins[dd];
      xr = fmaf(iv, xrw[dd * H_ + h], xr);
      xi = fmaf(iv, xiw[dd * H_ + h], xi);
      xn = fmaf(iv, xnw[dd * H_ + h], xn);
    }
    float r  = fast_sigmoid(xr + ar[u]);
    float ii = fast_sigmoid(xi + ai[u]);
    float ng = fast_tanh(xn + r * an[u]);
    float hp = hprev[node * H_ + h];
    hout[node * H_ + h] = (1.0f - ii) * ng + ii * hp;
  }
}

// ---------------- pred: batched output MLP + residual ----------------------
__global__ __launch_bounds__(256) void pred_kernel(
    const float* __restrict__ h_all, const float* __restrict__ data,
    const float* __restrict__ o1w, const float* __restrict__ o1b,
    const float* __restrict__ o2w, const float* __restrict__ o2b,
    const float* __restrict__ o3w, const float* __restrict__ o3b,
    float* __restrict__ out) {
  const int row0 = blockIdx.x * 16;
  const int tid = threadIdx.x;
  __shared__ float hlt[256][20];
  __shared__ float p1t[256][20];
  __shared__ float p2t[256][20];
  __shared__ float red2[16][16][4];
  for (int i = tid; i < 16 * 256; i += 256) {
    int r = i >> 8, f = i & 255;
    int row = row0 + r, t = row / NODES, nodeI = row % NODES;
    hlt[f][r] = h_all[(size_t)(t + 1) * NODES * H_ + nodeI * H_ + f];
  }
  __syncthreads();
  const int h = tid;
  float acc[16];
  #pragma unroll
  for (int r = 0; r < 16; ++r) acc[r] = 0.0f;
  #pragma unroll 2
  for (int f = 0; f < 256; ++f) {
    float w = o1w[f * H_ + h];
    const float4 g0 = *(const float4*)&hlt[f][0];
    const float4 g1 = *(const float4*)&hlt[f][4];
    const float4 g2 = *(const float4*)&hlt[f][8];
    const float4 g3 = *(const float4*)&hlt[f][12];
    float gv[16] = {g0.x,g0.y,g0.z,g0.w, g1.x,g1.y,g1.z,g1.w,
                    g2.x,g2.y,g2.z,g2.w, g3.x,g3.y,g3.z,g3.w};
    #pragma unroll
    for (int r = 0; r < 16; ++r) acc[r] = fmaf(gv[r], w, acc[r]);
  }
  {
    float bv = o1b[h];
    #pragma unroll
    for (int r = 0; r < 16; ++r) p1t[h][r] = fmaxf(acc[r] + bv, 0.0f);
  }
  __syncthreads();
  #pragma unroll
  for (int r = 0; r < 16; ++r) acc[r] = 0.0f;
  #pragma unroll 2
  for (int f = 0; f < 256; ++f) {
    float w = o2w[f * H_ + h];
    const float4 g0 = *(const float4*)&p1t[f][0];
    const float4 g1 = *(const float4*)&p1t[f][4];
    const float4 g2 = *(const float4*)&p1t[f][8];
    const float4 g3 = *(const float4*)&p1t[f][12];
    float gv[16] = {g0.x,g0.y,g0.z,g0.w, g1.x,g1.y,g1.z,g1.w,
                    g2.x,g2.y,g2.z,g2.w, g3.x,g3.y,g3.z,g3.w};
    #pragma unroll
    for (int r = 0; r < 16; ++r) acc[r] = fmaf(gv[r], w, acc[r]);
  }
  {
    float bv = o2b[h];
    #pragma unroll
    for (int r = 0; r < 16; ++r) p2t[h][r] = fmaxf(acc[r] + bv, 0.0f);
  }
  __syncthreads();
  {
    int r = tid >> 4, p = tid & 15;
    float s0 = 0, s1 = 0, s2 = 0, s3 = 0;
    #pragma unroll
    for (int q = 0; q < 16; ++q) {
      int f = p * 16 + q;
      float v = p2t[f][r];
      s0 = fmaf(v, o3w[f * 4 + 0], s0);
      s1 = fmaf(v, o3w[f * 4 + 1], s1);
      s2 = fmaf(v, o3w[f * 4 + 2], s2);
      s3 = fmaf(v, o3w[f * 4 + 3], s3);
    }
    red2[r][p][0] = s0; red2[r][p][1] = s1; red2[r][p][2] = s2; red2[r][p][3] = s3;
  }
  __syncthreads();
  if (tid < 64) {
    int r = tid >> 2, dd = tid & 3;
    float s = o3b[dd];
    #pragma unroll
    for (int p = 0; p < 16; ++p) s += red2[r][p][dd];
    int row = row0 + r, t = row / NODES, nodeI = row % NODES;
    s += data[(size_t)(nodeI * 10 + t) * 4 + dd];
    out[(size_t)(nodeI * TS + t) * 4 + dd] = s;
  }
}

// ---------------------------------------------------------------------------
extern "C" void kernel_launch(void* const* d_in, const int* in_sizes, int n_in,
                              void* d_out, int out_size, void* d_ws, size_t ws_size,
                              hipStream_t stream) {
  const float* data     = (const float*)d_in[0];
  const float* rel_type = (const float*)d_in[1];
  const float* w1  = (const float*)d_in[4];
  const float* b1  = (const float*)d_in[5];
  const float* w2  = (const float*)d_in[6];
  const float* b2  = (const float*)d_in[7];
  const float* hr  = (const float*)d_in[8];
  const float* hi  = (const float*)d_in[9];
  const float* hn  = (const float*)d_in[10];
  const float* inr_w = (const float*)d_in[11]; const float* inr_b = (const float*)d_in[12];
  const float* ini_w = (const float*)d_in[13]; const float* ini_b = (const float*)d_in[14];
  const float* inn_w = (const float*)d_in[15]; const float* inn_b = (const float*)d_in[16];
  const float* o1w = (const float*)d_in[17]; const float* o1b = (const float*)d_in[18];
  const float* o2w = (const float*)d_in[19]; const float* o2b = (const float*)d_in[20];
  const float* o3w = (const float*)d_in[21]; const float* o3b = (const float*)d_in[22];
  float* out = (float*)d_out;

  float* ws    = (float*)d_ws;
  float* h_all = ws;                        // [10][384][256]
  float* PA    = ws + 10 * NODES * H_;      // [3][384][256]
  float* PS    = PA + 3 * NODES * H_;       // [3][384][256]
  float* agg3  = PS + 3 * NODES * H_;       // [3][384][256] per-k partials

  hipMemsetAsync(h_all, 0, NODES * H_ * sizeof(float), stream);

  for (int t = 0; t < TS; ++t) {
    proj_kernel<<<288, 256, 0, stream>>>(h_all + (size_t)t * NODES * H_, w1, b1, PA, PS);
    edge_kernel<<<dim3(N_, B_, 6), 256, 0, stream>>>(PA, PS, rel_type, w2, b2, agg3);
    gru_kernel<<<192, 256, 0, stream>>>(h_all + (size_t)t * NODES * H_, agg3, data,
                                        hr, hi, hn,
                                        inr_w, inr_b, ini_w, ini_b, inn_w, inn_b,
                                        h_all + (size_t)(t + 1) * NODES * H_, t);
  }
  pred_kernel<<<216, 256, 0, stream>>>(h_all, data, o1w, o1b, o2w, o2b, o3w, o3b, out);
}

// Round 9
// 1587.234 us; speedup vs baseline: 1.1422x; 1.0419x over previous
//
#include <hip/hip_runtime.h>

// NRI decoder, fp32, factored layer-1 projections.
// B=8, N=48, T-1=9 steps, D=4, H=256, edge types 1..3, E=2256 (receiver-major).
//
// Round 7/8/9 bundle (per-kernel attributable via rocprof):
//  - edge: __launch_bounds__(256,4) spill fix (round-3 WRITE_SIZE=210MB @ VGPR=44).
//  - proj: 576 blocks (4-node tiles), explicit 8-wide load batching (round-3
//    accounting showed ~19us/dispatch = serial-load latency at 1.1 block/CU).
//  - gru: 384 blocks (2-node), 8-wide load batching (was 0.75 block/CU).

#define H_ 256
#define N_ 48
#define B_ 8
#define NODES 384     // B_*N_
#define TS 9          // T-1

__device__ __forceinline__ float fast_tanh(float x) {
  float e = __expf(2.0f * x);
  return 1.0f - 2.0f * __builtin_amdgcn_rcpf(1.0f + e);
}
__device__ __forceinline__ float fast_sigmoid(float x) {
  float e = __expf(-x);
  return __builtin_amdgcn_rcpf(1.0f + e);
}

// ---------------- proj: PA/PS node projections -----------------------------
// grid: 96 node-tiles * 6 mats = 576 blocks, 256 threads. Tile = 4 nodes.
__global__ __launch_bounds__(256, 4) void proj_kernel(
    const float* __restrict__ hidden, const float* __restrict__ w1,
    const float* __restrict__ b1, float* __restrict__ PA, float* __restrict__ PS) {
  const int mat  = blockIdx.x % 6;
  const int tile = blockIdx.x / 6;
  const int k = mat >> 1, part = mat & 1;
  const int node0 = tile * 4;
  __shared__ float hl[256][4];   // [f][nd]
  for (int i = threadIdx.x; i < 4 * 256; i += 256) {
    int nd = i >> 8, f = i & 255;
    hl[f][nd] = hidden[(node0 + nd) * H_ + f];
  }
  __syncthreads();
  const int h = threadIdx.x;
  const float* W = w1 + ((size_t)((k + 1) * 512 + part * 256)) * H_ + h;
  float acc0 = 0, acc1 = 0, acc2 = 0, acc3 = 0;
  for (int f0 = 0; f0 < 256; f0 += 8) {
    float wv[8];
    #pragma unroll
    for (int j = 0; j < 8; ++j) wv[j] = W[(f0 + j) * H_];   // 8 loads in flight
    #pragma unroll
    for (int j = 0; j < 8; ++j) {
      const float4 a = *(const float4*)&hl[f0 + j][0];
      acc0 = fmaf(a.x, wv[j], acc0);
      acc1 = fmaf(a.y, wv[j], acc1);
      acc2 = fmaf(a.z, wv[j], acc2);
      acc3 = fmaf(a.w, wv[j], acc3);
    }
  }
  float bias = part ? 0.0f : b1[(k + 1) * H_ + h];
  float* dst = (part ? PS : PA) + k * (NODES * H_) + node0 * H_ + h;
  dst[0]      = acc0 + bias;
  dst[H_]     = acc1 + bias;
  dst[2 * H_] = acc2 + bias;
  dst[3 * H_] = acc3 + bias;
}

// ---------------- edge: layer2 GEMM + weighting + aggregate ----------------
// grid: (48, 8, 6) z = k*2 + h-half; 256 threads. One (receiver, k, 128-h).
__global__ __launch_bounds__(256, 4) void edge_kernel(
    const float* __restrict__ PA, const float* __restrict__ PS,
    const float* __restrict__ rel_type, const float* __restrict__ w2,
    const float* __restrict__ b2, float* __restrict__ agg3) {
  const int n = blockIdx.x;
  const int b = blockIdx.y;
  const int k  = blockIdx.z >> 1;
  const int h0 = (blockIdx.z & 1) * 128;
  const int tid = threadIdx.x;
  const int node = b * N_ + n;

  __shared__ float a_l[256];        // PA row for this (receiver, k)
  __shared__ float m1t[32][49];     // [fi][e] transposed m1 chunk
  __shared__ float b2_l[128];
  __shared__ float rt_l[48];
  __shared__ float wred[32 * 128];  // w_l [32][128]; red [16][128] after last use
  float* w_l = wred;
  float* red = wred;

  a_l[tid] = PA[k * (NODES * H_) + node * H_ + tid];
  if (tid < 128) b2_l[tid] = b2[(k + 1) * H_ + h0 + tid];
  if (tid < 48)
    rt_l[tid] = (tid < 47) ? rel_type[(size_t)(b * 2256 + n * 47 + tid) * 4 + (k + 1)] : 0.0f;

  const float* W2k = w2 + (size_t)(k + 1) * H_ * H_ + h0;
  const float* PSk = PS + k * (NODES * H_) + b * N_ * H_;

  // staging index precompute
  const int fi0  = tid & 31;        // f-within-chunk for PS/m1 staging
  const int c4   = tid & 31;        // float4 column for W staging
  const int fiW0 = tid >> 5;        // base W row
  int srow[6];
  #pragma unroll
  for (int j = 0; j < 6; ++j) {
    int e = (tid + 256 * j) >> 5;             // 0..47
    int ee = (e < 47) ? e : 0;                // clamp pad row (value masked later)
    srow[j] = ee + (ee >= n);                 // sender node index
  }

  float4 wreg[4];
  float  psreg[6];

  #define LOAD_CHUNK(FC)                                                         \
    {                                                                            \
      _Pragma("unroll")                                                          \
      for (int j = 0; j < 4; ++j)                                                \
        wreg[j] = *(const float4*)&W2k[(size_t)((FC) * 32 + fiW0 + 8 * j) * H_ + c4 * 4]; \
      _Pragma("unroll")                                                          \
      for (int j = 0; j < 6; ++j)                                                \
        psreg[j] = PSk[srow[j] * H_ + (FC) * 32 + fi0];                          \
    }

  #define WRITE_CHUNK(FC)                                                        \
    {                                                                            \
      _Pragma("unroll")                                                          \
      for (int j = 0; j < 4; ++j)                                                \
        *(float4*)&w_l[(fiW0 + 8 * j) * 128 + c4 * 4] = wreg[j];                 \
      _Pragma("unroll")                                                          \
      for (int j = 0; j < 6; ++j) {                                              \
        int e = (tid + 256 * j) >> 5;                                            \
        float v = (e < 47) ? fast_tanh(a_l[(FC) * 32 + fi0] + psreg[j]) : 0.0f;  \
        m1t[fi0][e] = v;                                                         \
      }                                                                          \
    }

  LOAD_CHUNK(0);
  __syncthreads();        // invariant preloads (a_l) visible
  WRITE_CHUNK(0);
  __syncthreads();

  const int eg = tid >> 4;   // 0..15 -> edges {eg, eg+16, eg+32}
  const int hg = tid & 15;   // h = h0 + hg*4..+3  and  h0+64+hg*4..+3
  float acc0[8] = {0,0,0,0,0,0,0,0};
  float acc1[8] = {0,0,0,0,0,0,0,0};
  float acc2[8] = {0,0,0,0,0,0,0,0};

  for (int fc = 0; fc < 8; ++fc) {
    if (fc < 7) LOAD_CHUNK(fc + 1);     // in-flight across the compute phase
    #pragma unroll 8
    for (int fi = 0; fi < 32; ++fi) {
      float m0  = m1t[fi][eg];
      float m1v = m1t[fi][eg + 16];
      float m2v = m1t[fi][eg + 32];
      const float4 wa = *(const float4*)&w_l[fi * 128 + hg * 4];        // slot hg
      const float4 wb = *(const float4*)&w_l[fi * 128 + 64 + hg * 4];   // slot hg+16
      float wv[8] = {wa.x, wa.y, wa.z, wa.w, wb.x, wb.y, wb.z, wb.w};
      #pragma unroll
      for (int j = 0; j < 8; ++j) {
        acc0[j] = fmaf(m0,  wv[j], acc0[j]);
        acc1[j] = fmaf(m1v, wv[j], acc1[j]);
        acc2[j] = fmaf(m2v, wv[j], acc2[j]);
      }
    }
    __syncthreads();
    if (fc < 7) WRITE_CHUNK(fc + 1);
    __syncthreads();
  }

  // finish: bias, tanh, edge-type weight
  float agga[8];
  float r0 = rt_l[eg], r1 = rt_l[eg + 16], r2 = rt_l[eg + 32];
  #pragma unroll
  for (int j = 0; j < 8; ++j) {
    float bb = (j < 4) ? b2_l[hg * 4 + j] : b2_l[64 + hg * 4 + (j - 4)];
    float s = r0 * fast_tanh(acc0[j] + bb);
    s = fmaf(r1, fast_tanh(acc1[j] + bb), s);
    s = fmaf(r2, fast_tanh(acc2[j] + bb), s);
    agga[j] = s;
  }
  // red overlaps w_l: last w_l read was before the final barrier above
  *(float4*)&red[eg * 128 + hg * 4]      = make_float4(agga[0], agga[1], agga[2], agga[3]);
  *(float4*)&red[eg * 128 + 64 + hg * 4] = make_float4(agga[4], agga[5], agga[6], agga[7]);
  __syncthreads();
  if (tid < 128) {
    float s = 0.0f;
    #pragma unroll
    for (int p = 0; p < 16; ++p) s += red[p * 128 + tid];
    agg3[(size_t)(k * NODES + node) * H_ + h0 + tid] = s * (1.0f / 12.0f);
  }
}

// ---------------- gru: hidden update (sums 3 k-partials) --------------------
// grid: 192 node-pairs * 2 h-halves = 384 blocks, 256 threads. 2 nodes/block.
__global__ __launch_bounds__(256, 4) void gru_kernel(
    const float* __restrict__ hprev, const float* __restrict__ agg3,
    const float* __restrict__ data,
    const float* __restrict__ wr, const float* __restrict__ wi, const float* __restrict__ wn,
    const float* __restrict__ xrw, const float* __restrict__ xrb,
    const float* __restrict__ xiw, const float* __restrict__ xib,
    const float* __restrict__ xnw, const float* __restrict__ xnb,
    float* __restrict__ hout, int t) {
  const int node0 = (blockIdx.x >> 1) * 2;
  const int half  = blockIdx.x & 1;
  __shared__ float al[256][2];   // [f][nd]
  for (int i = threadIdx.x; i < 2 * 256; i += 256) {
    int nd = i >> 8, f = i & 255;
    size_t off = (size_t)(node0 + nd) * H_ + f;
    al[f][nd] = agg3[off] + agg3[(size_t)NODES * H_ + off] + agg3[2 * (size_t)NODES * H_ + off];
  }
  __syncthreads();
  const int hh = threadIdx.x & 127;
  const int h = half * 128 + hh;
  const int u = threadIdx.x >> 7;   // node select 0/1
  float ar = 0, ai = 0, an = 0;
  const float* pr = wr + h;
  const float* pi = wi + h;
  const float* pn = wn + h;
  for (int f0 = 0; f0 < 256; f0 += 8) {
    float wrv[8], wiv[8], wnv[8];
    #pragma unroll
    for (int j = 0; j < 8; ++j) {      // 24 loads in flight
      wrv[j] = pr[(f0 + j) * H_];
      wiv[j] = pi[(f0 + j) * H_];
      wnv[j] = pn[(f0 + j) * H_];
    }
    #pragma unroll
    for (int j = 0; j < 8; ++j) {
      float a = al[f0 + j][u];
      ar = fmaf(a, wrv[j], ar);
      ai = fmaf(a, wiv[j], ai);
      an = fmaf(a, wnv[j], an);
    }
  }
  {
    int node = node0 + u;
    const float* ins = data + (size_t)(node * 10 + t) * 4;   // data[b][n][t][:]
    float xr = xrb[h], xi = xib[h], xn = xnb[h];
    #pragma unroll
    for (int dd = 0; dd < 4; ++dd) {
      float iv = ins[dd];
      xr = fmaf(iv, xrw[dd * H_ + h], xr);
      xi = fmaf(iv, xiw[dd * H_ + h], xi);
      xn = fmaf(iv, xnw[dd * H_ + h], xn);
    }
    float r  = fast_sigmoid(xr + ar);
    float ii = fast_sigmoid(xi + ai);
    float ng = fast_tanh(xn + r * an);
    float hp = hprev[node * H_ + h];
    hout[node * H_ + h] = (1.0f - ii) * ng + ii * hp;
  }
}

// ---------------- pred: batched output MLP + residual ----------------------
__global__ __launch_bounds__(256) void pred_kernel(
    const float* __restrict__ h_all, const float* __restrict__ data,
    const float* __restrict__ o1w, const float* __restrict__ o1b,
    const float* __restrict__ o2w, const float* __restrict__ o2b,
    const float* __restrict__ o3w, const float* __restrict__ o3b,
    float* __restrict__ out) {
  const int row0 = blockIdx.x * 16;
  const int tid = threadIdx.x;
  __shared__ float hlt[256][20];
  __shared__ float p1t[256][20];
  __shared__ float p2t[256][20];
  __shared__ float red2[16][16][4];
  for (int i = tid; i < 16 * 256; i += 256) {
    int r = i >> 8, f = i & 255;
    int row = row0 + r, t = row / NODES, nodeI = row % NODES;
    hlt[f][r] = h_all[(size_t)(t + 1) * NODES * H_ + nodeI * H_ + f];
  }
  __syncthreads();
  const int h = tid;
  float acc[16];
  #pragma unroll
  for (int r = 0; r < 16; ++r) acc[r] = 0.0f;
  #pragma unroll 2
  for (int f = 0; f < 256; ++f) {
    float w = o1w[f * H_ + h];
    const float4 g0 = *(const float4*)&hlt[f][0];
    const float4 g1 = *(const float4*)&hlt[f][4];
    const float4 g2 = *(const float4*)&hlt[f][8];
    const float4 g3 = *(const float4*)&hlt[f][12];
    float gv[16] = {g0.x,g0.y,g0.z,g0.w, g1.x,g1.y,g1.z,g1.w,
                    g2.x,g2.y,g2.z,g2.w, g3.x,g3.y,g3.z,g3.w};
    #pragma unroll
    for (int r = 0; r < 16; ++r) acc[r] = fmaf(gv[r], w, acc[r]);
  }
  {
    float bv = o1b[h];
    #pragma unroll
    for (int r = 0; r < 16; ++r) p1t[h][r] = fmaxf(acc[r] + bv, 0.0f);
  }
  __syncthreads();
  #pragma unroll
  for (int r = 0; r < 16; ++r) acc[r] = 0.0f;
  #pragma unroll 2
  for (int f = 0; f < 256; ++f) {
    float w = o2w[f * H_ + h];
    const float4 g0 = *(const float4*)&p1t[f][0];
    const float4 g1 = *(const float4*)&p1t[f][4];
    const float4 g2 = *(const float4*)&p1t[f][8];
    const float4 g3 = *(const float4*)&p1t[f][12];
    float gv[16] = {g0.x,g0.y,g0.z,g0.w, g1.x,g1.y,g1.z,g1.w,
                    g2.x,g2.y,g2.z,g2.w, g3.x,g3.y,g3.z,g3.w};
    #pragma unroll
    for (int r = 0; r < 16; ++r) acc[r] = fmaf(gv[r], w, acc[r]);
  }
  {
    float bv = o2b[h];
    #pragma unroll
    for (int r = 0; r < 16; ++r) p2t[h][r] = fmaxf(acc[r] + bv, 0.0f);
  }
  __syncthreads();
  {
    int r = tid >> 4, p = tid & 15;
    float s0 = 0, s1 = 0, s2 = 0, s3 = 0;
    #pragma unroll
    for (int q = 0; q < 16; ++q) {
      int f = p * 16 + q;
      float v = p2t[f][r];
      s0 = fmaf(v, o3w[f * 4 + 0], s0);
      s1 = fmaf(v, o3w[f * 4 + 1], s1);
      s2 = fmaf(v, o3w[f * 4 + 2], s2);
      s3 = fmaf(v, o3w[f * 4 + 3], s3);
    }
    red2[r][p][0] = s0; red2[r][p][1] = s1; red2[r][p][2] = s2; red2[r][p][3] = s3;
  }
  __syncthreads();
  if (tid < 64) {
    int r = tid >> 2, dd = tid & 3;
    float s = o3b[dd];
    #pragma unroll
    for (int p = 0; p < 16; ++p) s += red2[r][p][dd];
    int row = row0 + r, t = row / NODES, nodeI = row % NODES;
    s += data[(size_t)(nodeI * 10 + t) * 4 + dd];
    out[(size_t)(nodeI * TS + t) * 4 + dd] = s;
  }
}

// ---------------------------------------------------------------------------
extern "C" void kernel_launch(void* const* d_in, const int* in_sizes, int n_in,
                              void* d_out, int out_size, void* d_ws, size_t ws_size,
                              hipStream_t stream) {
  const float* data     = (const float*)d_in[0];
  const float* rel_type = (const float*)d_in[1];
  const float* w1  = (const float*)d_in[4];
  const float* b1  = (const float*)d_in[5];
  const float* w2  = (const float*)d_in[6];
  const float* b2  = (const float*)d_in[7];
  const float* hr  = (const float*)d_in[8];
  const float* hi  = (const float*)d_in[9];
  const float* hn  = (const float*)d_in[10];
  const float* inr_w = (const float*)d_in[11]; const float* inr_b = (const float*)d_in[12];
  const float* ini_w = (const float*)d_in[13]; const float* ini_b = (const float*)d_in[14];
  const float* inn_w = (const float*)d_in[15]; const float* inn_b = (const float*)d_in[16];
  const float* o1w = (const float*)d_in[17]; const float* o1b = (const float*)d_in[18];
  const float* o2w = (const float*)d_in[19]; const float* o2b = (const float*)d_in[20];
  const float* o3w = (const float*)d_in[21]; const float* o3b = (const float*)d_in[22];
  float* out = (float*)d_out;

  float* ws    = (float*)d_ws;
  float* h_all = ws;                        // [10][384][256]
  float* PA    = ws + 10 * NODES * H_;      // [3][384][256]
  float* PS    = PA + 3 * NODES * H_;       // [3][384][256]
  float* agg3  = PS + 3 * NODES * H_;       // [3][384][256] per-k partials

  hipMemsetAsync(h_all, 0, NODES * H_ * sizeof(float), stream);

  for (int t = 0; t < TS; ++t) {
    proj_kernel<<<576, 256, 0, stream>>>(h_all + (size_t)t * NODES * H_, w1, b1, PA, PS);
    edge_kernel<<<dim3(N_, B_, 6), 256, 0, stream>>>(PA, PS, rel_type, w2, b2, agg3);
    gru_kernel<<<384, 256, 0, stream>>>(h_all + (size_t)t * NODES * H_, agg3, data,
                                        hr, hi, hn,
                                        inr_w, inr_b, ini_w, ini_b, inn_w, inn_b,
                                        h_all + (size_t)(t + 1) * NODES * H_, t);
  }
  pred_kernel<<<216, 256, 0, stream>>>(h_all, data, o1w, o1b, o2w, o2b, o3w, o3b, out);
}

// Round 10
// 1359.970 us; speedup vs baseline: 1.3331x; 1.1671x over previous
//
#include <hip/hip_runtime.h>

// NRI decoder, fp32, factored layer-1 projections.
// B=8, N=48, T-1=9 steps, D=4, H=256, edge types 1..3, E=2256 (receiver-major).
//
// Round 10 change (edge_kernel): named-scalar staging.
//   Round-9 refuted the launch_bounds spill theory: VGPR=44 / WRITE=210MB
//   unchanged. Real mechanism (rule #20): the wreg[4]/psreg[6]/srow[6] LOCAL
//   ARRAYS in the staging macros were allocated to scratch (localMem), not
//   registers -- VGPR dropped 76->44 when they were added (round 2->3) and
//   scratch round-trips produced the 210MB/dispatch writes. launch_bounds
//   cannot fix that. Fix: zero arrays -- named scalars wA..wD, p0..p5,
//   sr0..sr5, fully hand-unrolled staging, e_j = (tid>>5) + 8*j.

#define H_ 256
#define N_ 48
#define B_ 8
#define NODES 384     // B_*N_
#define TS 9          // T-1

__device__ __forceinline__ float fast_tanh(float x) {
  float e = __expf(2.0f * x);
  return 1.0f - 2.0f * __builtin_amdgcn_rcpf(1.0f + e);
}
__device__ __forceinline__ float fast_sigmoid(float x) {
  float e = __expf(-x);
  return __builtin_amdgcn_rcpf(1.0f + e);
}

// ---------------- proj: PA/PS node projections -----------------------------
// grid: 96 node-tiles * 6 mats = 576 blocks, 256 threads. Tile = 4 nodes.
__global__ __launch_bounds__(256, 4) void proj_kernel(
    const float* __restrict__ hidden, const float* __restrict__ w1,
    const float* __restrict__ b1, float* __restrict__ PA, float* __restrict__ PS) {
  const int mat  = blockIdx.x % 6;
  const int tile = blockIdx.x / 6;
  const int k = mat >> 1, part = mat & 1;
  const int node0 = tile * 4;
  __shared__ float hl[256][4];   // [f][nd]
  for (int i = threadIdx.x; i < 4 * 256; i += 256) {
    int nd = i >> 8, f = i & 255;
    hl[f][nd] = hidden[(node0 + nd) * H_ + f];
  }
  __syncthreads();
  const int h = threadIdx.x;
  const float* W = w1 + ((size_t)((k + 1) * 512 + part * 256)) * H_ + h;
  float acc0 = 0, acc1 = 0, acc2 = 0, acc3 = 0;
  for (int f0 = 0; f0 < 256; f0 += 8) {
    float wv[8];
    #pragma unroll
    for (int j = 0; j < 8; ++j) wv[j] = W[(f0 + j) * H_];   // 8 loads in flight
    #pragma unroll
    for (int j = 0; j < 8; ++j) {
      const float4 a = *(const float4*)&hl[f0 + j][0];
      acc0 = fmaf(a.x, wv[j], acc0);
      acc1 = fmaf(a.y, wv[j], acc1);
      acc2 = fmaf(a.z, wv[j], acc2);
      acc3 = fmaf(a.w, wv[j], acc3);
    }
  }
  float bias = part ? 0.0f : b1[(k + 1) * H_ + h];
  float* dst = (part ? PS : PA) + k * (NODES * H_) + node0 * H_ + h;
  dst[0]      = acc0 + bias;
  dst[H_]     = acc1 + bias;
  dst[2 * H_] = acc2 + bias;
  dst[3 * H_] = acc3 + bias;
}

// ---------------- edge: layer2 GEMM + weighting + aggregate ----------------
// grid: (48, 8, 6) z = k*2 + h-half; 256 threads. One (receiver, k, 128-h).
__global__ __launch_bounds__(256, 4) void edge_kernel(
    const float* __restrict__ PA, const float* __restrict__ PS,
    const float* __restrict__ rel_type, const float* __restrict__ w2,
    const float* __restrict__ b2, float* __restrict__ agg3) {
  const int n = blockIdx.x;
  const int b = blockIdx.y;
  const int k  = blockIdx.z >> 1;
  const int h0 = (blockIdx.z & 1) * 128;
  const int tid = threadIdx.x;
  const int node = b * N_ + n;

  __shared__ float a_l[256];        // PA row for this (receiver, k)
  __shared__ float m1t[32][49];     // [fi][e] transposed m1 chunk
  __shared__ float b2_l[128];
  __shared__ float rt_l[48];
  __shared__ float wred[32 * 128];  // w_l [32][128]; red [16][128] after last use
  float* w_l = wred;
  float* red = wred;

  a_l[tid] = PA[k * (NODES * H_) + node * H_ + tid];
  if (tid < 128) b2_l[tid] = b2[(k + 1) * H_ + h0 + tid];
  if (tid < 48)
    rt_l[tid] = (tid < 47) ? rel_type[(size_t)(b * 2256 + n * 47 + tid) * 4 + (k + 1)] : 0.0f;

  const float* W2k = w2 + (size_t)(k + 1) * H_ * H_ + h0;
  const float* PSk = PS + k * (NODES * H_) + b * N_ * H_;

  // staging indices: thread (fiW0, c4) stages W rows fiW0+8j; thread fi0
  // stages m1 column-chunk e_j = ebase + 8j (only j=5 can be the pad e=47).
  const int fi0   = tid & 31;
  const int c4    = tid & 31;
  const int fiW0  = tid >> 5;       // 0..7
  const int ebase = tid >> 5;       // 0..7
  const int e0 = ebase,      e1 = ebase + 8,  e2 = ebase + 16;
  const int e3 = ebase + 24, e4 = ebase + 32, e5 = ebase + 40;   // e5==47 -> pad
  const int ee5 = (e5 < 47) ? e5 : 0;
  const int sr0 = e0 + (e0 >= n);
  const int sr1 = e1 + (e1 >= n);
  const int sr2 = e2 + (e2 >= n);
  const int sr3 = e3 + (e3 >= n);
  const int sr4 = e4 + (e4 >= n);
  const int sr5 = ee5 + (ee5 >= n);

  // named-scalar staging state (NO arrays -> stays in VGPRs, rule #20)
  float4 wA, wB, wC, wD;
  float p0, p1, p2, p3, p4, p5;

  #define LOADC(FC) do {                                               \
    const float* Wp = W2k + (size_t)((FC) * 32 + fiW0) * H_ + c4 * 4;  \
    wA = *(const float4*)(Wp);                                         \
    wB = *(const float4*)(Wp + 8 * H_);                                \
    wC = *(const float4*)(Wp + 16 * H_);                               \
    wD = *(const float4*)(Wp + 24 * H_);                               \
    const float* Pp = PSk + (FC) * 32 + fi0;                           \
    p0 = Pp[sr0 * H_]; p1 = Pp[sr1 * H_]; p2 = Pp[sr2 * H_];           \
    p3 = Pp[sr3 * H_]; p4 = Pp[sr4 * H_]; p5 = Pp[sr5 * H_];           \
  } while (0)

  #define WRITEC(FC) do {                                              \
    float* wp = w_l + fiW0 * 128 + c4 * 4;                             \
    *(float4*)(wp)           = wA;                                     \
    *(float4*)(wp + 8 * 128) = wB;                                     \
    *(float4*)(wp + 16 * 128) = wC;                                    \
    *(float4*)(wp + 24 * 128) = wD;                                    \
    float av = a_l[(FC) * 32 + fi0];                                   \
    m1t[fi0][e0] = fast_tanh(av + p0);                                 \
    m1t[fi0][e1] = fast_tanh(av + p1);                                 \
    m1t[fi0][e2] = fast_tanh(av + p2);                                 \
    m1t[fi0][e3] = fast_tanh(av + p3);                                 \
    m1t[fi0][e4] = fast_tanh(av + p4);                                 \
    m1t[fi0][e5] = (e5 < 47) ? fast_tanh(av + p5) : 0.0f;              \
  } while (0)

  LOADC(0);
  __syncthreads();        // invariant preloads (a_l) visible
  WRITEC(0);
  __syncthreads();

  const int eg = tid >> 4;   // 0..15 -> edges {eg, eg+16, eg+32}
  const int hg = tid & 15;   // h = h0 + hg*4..+3  and  h0+64+hg*4..+3
  float acc0[8] = {0,0,0,0,0,0,0,0};
  float acc1[8] = {0,0,0,0,0,0,0,0};
  float acc2[8] = {0,0,0,0,0,0,0,0};

  for (int fc = 0; fc < 8; ++fc) {
    if (fc < 7) LOADC(fc + 1);     // stays in flight across the compute phase
    #pragma unroll 8
    for (int fi = 0; fi < 32; ++fi) {
      float m0  = m1t[fi][eg];
      float m1v = m1t[fi][eg + 16];
      float m2v = m1t[fi][eg + 32];
      const float4 wa = *(const float4*)&w_l[fi * 128 + hg * 4];        // slot hg
      const float4 wb = *(const float4*)&w_l[fi * 128 + 64 + hg * 4];   // slot hg+16
      float wv[8] = {wa.x, wa.y, wa.z, wa.w, wb.x, wb.y, wb.z, wb.w};
      #pragma unroll
      for (int j = 0; j < 8; ++j) {
        acc0[j] = fmaf(m0,  wv[j], acc0[j]);
        acc1[j] = fmaf(m1v, wv[j], acc1[j]);
        acc2[j] = fmaf(m2v, wv[j], acc2[j]);
      }
    }
    __syncthreads();
    if (fc < 7) WRITEC(fc + 1);
    __syncthreads();
  }

  // finish: bias, tanh, edge-type weight
  float agga[8];
  float r0 = rt_l[eg], r1 = rt_l[eg + 16], r2 = rt_l[eg + 32];
  #pragma unroll
  for (int j = 0; j < 8; ++j) {
    float bb = (j < 4) ? b2_l[hg * 4 + j] : b2_l[64 + hg * 4 + (j - 4)];
    float s = r0 * fast_tanh(acc0[j] + bb);
    s = fmaf(r1, fast_tanh(acc1[j] + bb), s);
    s = fmaf(r2, fast_tanh(acc2[j] + bb), s);
    agga[j] = s;
  }
  // red overlaps w_l: last w_l read was before the final barrier above
  *(float4*)&red[eg * 128 + hg * 4]      = make_float4(agga[0], agga[1], agga[2], agga[3]);
  *(float4*)&red[eg * 128 + 64 + hg * 4] = make_float4(agga[4], agga[5], agga[6], agga[7]);
  __syncthreads();
  if (tid < 128) {
    float s = 0.0f;
    #pragma unroll
    for (int p = 0; p < 16; ++p) s += red[p * 128 + tid];
    agg3[(size_t)(k * NODES + node) * H_ + h0 + tid] = s * (1.0f / 12.0f);
  }
}

// ---------------- gru: hidden update (sums 3 k-partials) --------------------
// grid: 192 node-pairs * 2 h-halves = 384 blocks, 256 threads. 2 nodes/block.
__global__ __launch_bounds__(256, 4) void gru_kernel(
    const float* __restrict__ hprev, const float* __restrict__ agg3,
    const float* __restrict__ data,
    const float* __restrict__ wr, const float* __restrict__ wi, const float* __restrict__ wn,
    const float* __restrict__ xrw, const float* __restrict__ xrb,
    const float* __restrict__ xiw, const float* __restrict__ xib,
    const float* __restrict__ xnw, const float* __restrict__ xnb,
    float* __restrict__ hout, int t) {
  const int node0 = (blockIdx.x >> 1) * 2;
  const int half  = blockIdx.x & 1;
  __shared__ float al[256][2];   // [f][nd]
  for (int i = threadIdx.x; i < 2 * 256; i += 256) {
    int nd = i >> 8, f = i & 255;
    size_t off = (size_t)(node0 + nd) * H_ + f;
    al[f][nd] = agg3[off] + agg3[(size_t)NODES * H_ + off] + agg3[2 * (size_t)NODES * H_ + off];
  }
  __syncthreads();
  const int hh = threadIdx.x & 127;
  const int h = half * 128 + hh;
  const int u = threadIdx.x >> 7;   // node select 0/1
  float ar = 0, ai = 0, an = 0;
  const float* pr = wr + h;
  const float* pi = wi + h;
  const float* pn = wn + h;
  for (int f0 = 0; f0 < 256; f0 += 8) {
    float wrv[8], wiv[8], wnv[8];
    #pragma unroll
    for (int j = 0; j < 8; ++j) {      // 24 loads in flight
      wrv[j] = pr[(f0 + j) * H_];
      wiv[j] = pi[(f0 + j) * H_];
      wnv[j] = pn[(f0 + j) * H_];
    }
    #pragma unroll
    for (int j = 0; j < 8; ++j) {
      float a = al[f0 + j][u];
      ar = fmaf(a, wrv[j], ar);
      ai = fmaf(a, wiv[j], ai);
      an = fmaf(a, wnv[j], an);
    }
  }
  {
    int node = node0 + u;
    const float* ins = data + (size_t)(node * 10 + t) * 4;   // data[b][n][t][:]
    float xr = xrb[h], xi = xib[h], xn = xnb[h];
    #pragma unroll
    for (int dd = 0; dd < 4; ++dd) {
      float iv = ins[dd];
      xr = fmaf(iv, xrw[dd * H_ + h], xr);
      xi = fmaf(iv, xiw[dd * H_ + h], xi);
      xn = fmaf(iv, xnw[dd * H_ + h], xn);
    }
    float r  = fast_sigmoid(xr + ar);
    float ii = fast_sigmoid(xi + ai);
    float ng = fast_tanh(xn + r * an);
    float hp = hprev[node * H_ + h];
    hout[node * H_ + h] = (1.0f - ii) * ng + ii * hp;
  }
}

// ---------------- pred: batched output MLP + residual ----------------------
__global__ __launch_bounds__(256) void pred_kernel(
    const float* __restrict__ h_all, const float* __restrict__ data,
    const float* __restrict__ o1w, const float* __restrict__ o1b,
    const float* __restrict__ o2w, const float* __restrict__ o2b,
    const float* __restrict__ o3w, const float* __restrict__ o3b,
    float* __restrict__ out) {
  const int row0 = blockIdx.x * 16;
  const int tid = threadIdx.x;
  __shared__ float hlt[256][20];
  __shared__ float p1t[256][20];
  __shared__ float p2t[256][20];
  __shared__ float red2[16][16][4];
  for (int i = tid; i < 16 * 256; i += 256) {
    int r = i >> 8, f = i & 255;
    int row = row0 + r, t = row / NODES, nodeI = row % NODES;
    hlt[f][r] = h_all[(size_t)(t + 1) * NODES * H_ + nodeI * H_ + f];
  }
  __syncthreads();
  const int h = tid;
  float acc[16];
  #pragma unroll
  for (int r = 0; r < 16; ++r) acc[r] = 0.0f;
  #pragma unroll 2
  for (int f = 0; f < 256; ++f) {
    float w = o1w[f * H_ + h];
    const float4 g0 = *(const float4*)&hlt[f][0];
    const float4 g1 = *(const float4*)&hlt[f][4];
    const float4 g2 = *(const float4*)&hlt[f][8];
    const float4 g3 = *(const float4*)&hlt[f][12];
    float gv[16] = {g0.x,g0.y,g0.z,g0.w, g1.x,g1.y,g1.z,g1.w,
                    g2.x,g2.y,g2.z,g2.w, g3.x,g3.y,g3.z,g3.w};
    #pragma unroll
    for (int r = 0; r < 16; ++r) acc[r] = fmaf(gv[r], w, acc[r]);
  }
  {
    float bv = o1b[h];
    #pragma unroll
    for (int r = 0; r < 16; ++r) p1t[h][r] = fmaxf(acc[r] + bv, 0.0f);
  }
  __syncthreads();
  #pragma unroll
  for (int r = 0; r < 16; ++r) acc[r] = 0.0f;
  #pragma unroll 2
  for (int f = 0; f < 256; ++f) {
    float w = o2w[f * H_ + h];
    const float4 g0 = *(const float4*)&p1t[f][0];
    const float4 g1 = *(const float4*)&p1t[f][4];
    const float4 g2 = *(const float4*)&p1t[f][8];
    const float4 g3 = *(const float4*)&p1t[f][12];
    float gv[16] = {g0.x,g0.y,g0.z,g0.w, g1.x,g1.y,g1.z,g1.w,
                    g2.x,g2.y,g2.z,g2.w, g3.x,g3.y,g3.z,g3.w};
    #pragma unroll
    for (int r = 0; r < 16; ++r) acc[r] = fmaf(gv[r], w, acc[r]);
  }
  {
    float bv = o2b[h];
    #pragma unroll
    for (int r = 0; r < 16; ++r) p2t[h][r] = fmaxf(acc[r] + bv, 0.0f);
  }
  __syncthreads();
  {
    int r = tid >> 4, p = tid & 15;
    float s0 = 0, s1 = 0, s2 = 0, s3 = 0;
    #pragma unroll
    for (int q = 0; q < 16; ++q) {
      int f = p * 16 + q;
      float v = p2t[f][r];
      s0 = fmaf(v, o3w[f * 4 + 0], s0);
      s1 = fmaf(v, o3w[f * 4 + 1], s1);
      s2 = fmaf(v, o3w[f * 4 + 2], s2);
      s3 = fmaf(v, o3w[f * 4 + 3], s3);
    }
    red2[r][p][0] = s0; red2[r][p][1] = s1; red2[r][p][2] = s2; red2[r][p][3] = s3;
  }
  __syncthreads();
  if (tid < 64) {
    int r = tid >> 2, dd = tid & 3;
    float s = o3b[dd];
    #pragma unroll
    for (int p = 0; p < 16; ++p) s += red2[r][p][dd];
    int row = row0 + r, t = row / NODES, nodeI = row % NODES;
    s += data[(size_t)(nodeI * 10 + t) * 4 + dd];
    out[(size_t)(nodeI * TS + t) * 4 + dd] = s;
  }
}

// ---------------------------------------------------------------------------
extern "C" void kernel_launch(void* const* d_in, const int* in_sizes, int n_in,
                              void* d_out, int out_size, void* d_ws, size_t ws_size,
                              hipStream_t stream) {
  const float* data     = (const float*)d_in[0];
  const float* rel_type = (const float*)d_in[1];
  const float* w1  = (const float*)d_in[4];
  const float* b1  = (const float*)d_in[5];
  const float* w2  = (const float*)d_in[6];
  const float* b2  = (const float*)d_in[7];
  const float* hr  = (const float*)d_in[8];
  const float* hi  = (const float*)d_in[9];
  const float* hn  = (const float*)d_in[10];
  const float* inr_w = (const float*)d_in[11]; const float* inr_b = (const float*)d_in[12];
  const float* ini_w = (const float*)d_in[13]; const float* ini_b = (const float*)d_in[14];
  const float* inn_w = (const float*)d_in[15]; const float* inn_b = (const float*)d_in[16];
  const float* o1w = (const float*)d_in[17]; const float* o1b = (const float*)d_in[18];
  const float* o2w = (const float*)d_in[19]; const float* o2b = (const float*)d_in[20];
  const float* o3w = (const float*)d_in[21]; const float* o3b = (const float*)d_in[22];
  float* out = (float*)d_out;

  float* ws    = (float*)d_ws;
  float* h_all = ws;                        // [10][384][256]
  float* PA    = ws + 10 * NODES * H_;      // [3][384][256]
  float* PS    = PA + 3 * NODES * H_;       // [3][384][256]
  float* agg3  = PS + 3 * NODES * H_;       // [3][384][256] per-k partials

  hipMemsetAsync(h_all, 0, NODES * H_ * sizeof(float), stream);

  for (int t = 0; t < TS; ++t) {
    proj_kernel<<<576, 256, 0, stream>>>(h_all + (size_t)t * NODES * H_, w1, b1, PA, PS);
    edge_kernel<<<dim3(N_, B_, 6), 256, 0, stream>>>(PA, PS, rel_type, w2, b2, agg3);
    gru_kernel<<<384, 256, 0, stream>>>(h_all + (size_t)t * NODES * H_, agg3, data,
                                        hr, hi, hn,
                                        inr_w, inr_b, ini_w, ini_b, inn_w, inn_b,
                                        h_all + (size_t)(t + 1) * NODES * H_, t);
  }
  pred_kernel<<<216, 256, 0, stream>>>(h_all, data, o1w, o1b, o2w, o2b, o3w, o3b, out);
}

// Round 11
// 693.799 us; speedup vs baseline: 2.6131x; 1.9602x over previous
//
#include <hip/hip_runtime.h>

// NRI decoder. B=8, N=48, T-1=9, D=4, H=256, edge types 1..3, E=2256.
//
// Round 11: edge_kernel rewritten as split-bf16 MFMA GEMM.
//  - w2cvt (once/launch): W2[k][f][h] -> bf16 hi/lo in B-fragment order
//    [(k*8+ks)*16+nt][lane][8], read straight from global in the hot loop.
//  - edge block = (n,b,k), grid (48,8,3): m1[48][256]=tanh(PA+PS) staged once
//    to LDS as bf16 hi/lo (XOR-swizzle f^((e&7)<<3) -- A-frag reads are
//    row-strided, 16-way conflict unswizzled). ONE barrier per block.
//  - 288 mfma_16x16x32_bf16/wave (3-term split: hi*hi + lo*hi + hi*lo).
//  - epilogue: D col=lane&15, row=(lane>>4)*4+reg (m89-verified layout);
//    bias+tanh+rt, shfl_xor(16,32) reduce over e, lk==0 stores agg3.
//  - pad row e=47: m1 row zeroed, rt_l[47]=0.

#define H_ 256
#define N_ 48
#define B_ 8
#define NODES 384
#define TS 9

typedef __attribute__((ext_vector_type(8))) short bfrag;   // 8 bf16 (4 VGPR)
typedef __attribute__((ext_vector_type(4))) float ffrag;   // 4 f32 acc

__device__ __forceinline__ float fast_tanh(float x) {
  float e = __expf(2.0f * x);
  return 1.0f - 2.0f * __builtin_amdgcn_rcpf(1.0f + e);
}
__device__ __forceinline__ float fast_sigmoid(float x) {
  float e = __expf(-x);
  return __builtin_amdgcn_rcpf(1.0f + e);
}
__device__ __forceinline__ unsigned short f2bf(float x) {   // rne f32->bf16
  unsigned u = __float_as_uint(x);
  return (unsigned short)((u + 0x7FFF + ((u >> 16) & 1)) >> 16);
}
__device__ __forceinline__ float bf2f(unsigned short b) {
  return __uint_as_float(((unsigned)b) << 16);
}

// ---------------- w2cvt: W2 -> bf16 hi/lo in B-fragment order (once) -------
// grid 384 = (k*8+ks)*16+nt, 64 threads. out[blk][lane][j] =
//   W2[(k+1)][f=ks*32+(lane>>4)*8+j][h=nt*16+(lane&15)]
__global__ __launch_bounds__(64) void w2cvt_kernel(
    const float* __restrict__ w2,
    unsigned short* __restrict__ Bhi, unsigned short* __restrict__ Blo) {
  const int blk = blockIdx.x;
  const int l = threadIdx.x;
  const int nt = blk & 15, ks = (blk >> 4) & 7, k = blk >> 7;
  const int h = nt * 16 + (l & 15);
  const int fbase = ks * 32 + (l >> 4) * 8;
  const float* src = w2 + (size_t)(k + 1) * H_ * H_;
  const size_t ob = (size_t)blk * 512 + l * 8;
  #pragma unroll
  for (int j = 0; j < 8; ++j) {
    float v = src[(size_t)(fbase + j) * H_ + h];
    unsigned short hi = f2bf(v);
    Bhi[ob + j] = hi;
    Blo[ob + j] = f2bf(v - bf2f(hi));
  }
}

// ---------------- proj: PA/PS node projections (unchanged) -----------------
__global__ __launch_bounds__(256, 4) void proj_kernel(
    const float* __restrict__ hidden, const float* __restrict__ w1,
    const float* __restrict__ b1, float* __restrict__ PA, float* __restrict__ PS) {
  const int mat  = blockIdx.x % 6;
  const int tile = blockIdx.x / 6;
  const int k = mat >> 1, part = mat & 1;
  const int node0 = tile * 4;
  __shared__ float hl[256][4];
  for (int i = threadIdx.x; i < 4 * 256; i += 256) {
    int nd = i >> 8, f = i & 255;
    hl[f][nd] = hidden[(node0 + nd) * H_ + f];
  }
  __syncthreads();
  const int h = threadIdx.x;
  const float* W = w1 + ((size_t)((k + 1) * 512 + part * 256)) * H_ + h;
  float acc0 = 0, acc1 = 0, acc2 = 0, acc3 = 0;
  for (int f0 = 0; f0 < 256; f0 += 8) {
    float wv[8];
    #pragma unroll
    for (int j = 0; j < 8; ++j) wv[j] = W[(f0 + j) * H_];
    #pragma unroll
    for (int j = 0; j < 8; ++j) {
      const float4 a = *(const float4*)&hl[f0 + j][0];
      acc0 = fmaf(a.x, wv[j], acc0);
      acc1 = fmaf(a.y, wv[j], acc1);
      acc2 = fmaf(a.z, wv[j], acc2);
      acc3 = fmaf(a.w, wv[j], acc3);
    }
  }
  float bias = part ? 0.0f : b1[(k + 1) * H_ + h];
  float* dst = (part ? PS : PA) + k * (NODES * H_) + node0 * H_ + h;
  dst[0]      = acc0 + bias;
  dst[H_]     = acc1 + bias;
  dst[2 * H_] = acc2 + bias;
  dst[3 * H_] = acc3 + bias;
}

// ---------------- edge: split-bf16 MFMA GEMM + aggregate -------------------
// grid (48, 8, 3) = (recv n, b, k); 256 threads = 4 waves, wave wv owns
// n-cols wv*64..+63 (4 N-tiles), all 3 M-tiles (48 edge rows), K=256.
__global__ __launch_bounds__(256, 3) void edge_kernel(
    const float* __restrict__ PA, const float* __restrict__ PS,
    const float* __restrict__ rel_type,
    const unsigned short* __restrict__ Bhi, const unsigned short* __restrict__ Blo,
    const float* __restrict__ b2, float* __restrict__ agg3) {
  const int n = blockIdx.x;
  const int b = blockIdx.y;
  const int k = blockIdx.z;
  const int tid = threadIdx.x;
  const int node = b * N_ + n;

  __shared__ unsigned short m1hi[48 * 256];
  __shared__ unsigned short m1lo[48 * 256];
  __shared__ float rt_l[48];

  if (tid < 48)
    rt_l[tid] = (tid < 47) ? rel_type[(size_t)(b * 2256 + n * 47 + tid) * 4 + (k + 1)] : 0.0f;

  // ---- stage m1: thread owns column f=tid for all 48 rows ----
  {
    const float av = PA[(size_t)k * NODES * H_ + (size_t)node * H_ + tid];
    const float* PSk = PS + (size_t)k * NODES * H_ + (size_t)b * N_ * H_;

    #define STROW(E, Q) do {                                          \
      float v_ = ((E) < 47) ? fast_tanh(av + (Q)) : 0.0f;             \
      unsigned short hi_ = f2bf(v_);                                  \
      int idx_ = (E) * 256 + (tid ^ (((E) & 7) << 3));                \
      m1hi[idx_] = hi_;                                               \
      m1lo[idx_] = f2bf(v_ - bf2f(hi_));                              \
    } while (0)

    #pragma unroll
    for (int g = 0; g < 8; ++g) {     // 8 groups x 6 rows, named scalars only
      const int j0 = g * 6;
      const int E0 = j0, E1 = j0 + 1, E2 = j0 + 2, E3 = j0 + 3, E4 = j0 + 4, E5 = j0 + 5;
      const int s0 = (E0 < 47) ? E0 + (E0 >= n) : 0;
      const int s1 = (E1 < 47) ? E1 + (E1 >= n) : 0;
      const int s2 = (E2 < 47) ? E2 + (E2 >= n) : 0;
      const int s3 = (E3 < 47) ? E3 + (E3 >= n) : 0;
      const int s4 = (E4 < 47) ? E4 + (E4 >= n) : 0;
      const int s5 = (E5 < 47) ? E5 + (E5 >= n) : 0;
      float q0 = PSk[(size_t)s0 * H_ + tid];
      float q1 = PSk[(size_t)s1 * H_ + tid];
      float q2 = PSk[(size_t)s2 * H_ + tid];
      float q3 = PSk[(size_t)s3 * H_ + tid];
      float q4 = PSk[(size_t)s4 * H_ + tid];
      float q5 = PSk[(size_t)s5 * H_ + tid];
      STROW(E0, q0); STROW(E1, q1); STROW(E2, q2);
      STROW(E3, q3); STROW(E4, q4); STROW(E5, q5);
    }
  }
  __syncthreads();   // the ONLY barrier

  // ---- MFMA K-loop ----
  const int lane = tid & 63;
  const int wv = tid >> 6;           // 0..3
  const int lm = lane & 15;          // A row / B col / D col
  const int lk = lane >> 4;          // k-chunk select

  ffrag a00 = {0,0,0,0}, a01 = {0,0,0,0}, a02 = {0,0,0,0}, a03 = {0,0,0,0};
  ffrag a10 = {0,0,0,0}, a11 = {0,0,0,0}, a12 = {0,0,0,0}, a13 = {0,0,0,0};
  ffrag a20 = {0,0,0,0}, a21 = {0,0,0,0}, a22 = {0,0,0,0}, a23 = {0,0,0,0};

  const unsigned short* Bh = Bhi + (size_t)k * 65536 + (size_t)(wv * 4) * 512 + lane * 8;
  const unsigned short* Bl = Blo + (size_t)k * 65536 + (size_t)(wv * 4) * 512 + lane * 8;

  #define MFMA3(ACC, AH, AL, BH, BL) do {                                      \
    ACC = __builtin_amdgcn_mfma_f32_16x16x32_bf16(AH, BH, ACC, 0, 0, 0);       \
    ACC = __builtin_amdgcn_mfma_f32_16x16x32_bf16(AL, BH, ACC, 0, 0, 0);       \
    ACC = __builtin_amdgcn_mfma_f32_16x16x32_bf16(AH, BL, ACC, 0, 0, 0);       \
  } while (0)

  #pragma unroll
  for (int ks = 0; ks < 8; ++ks) {
    const int colsw = (ks * 32 + lk * 8) ^ ((lm & 7) << 3);
    bfrag ah0 = *(const bfrag*)&m1hi[lm * 256 + colsw];
    bfrag ah1 = *(const bfrag*)&m1hi[(16 + lm) * 256 + colsw];
    bfrag ah2 = *(const bfrag*)&m1hi[(32 + lm) * 256 + colsw];
    bfrag al0 = *(const bfrag*)&m1lo[lm * 256 + colsw];
    bfrag al1 = *(const bfrag*)&m1lo[(16 + lm) * 256 + colsw];
    bfrag al2 = *(const bfrag*)&m1lo[(32 + lm) * 256 + colsw];
    const unsigned short* bh = Bh + ks * 8192;   // (ks*16)*512
    const unsigned short* bl = Bl + ks * 8192;
    bfrag vh, vl;
    vh = *(const bfrag*)&bh[0];        vl = *(const bfrag*)&bl[0];
    MFMA3(a00, ah0, al0, vh, vl); MFMA3(a10, ah1, al1, vh, vl); MFMA3(a20, ah2, al2, vh, vl);
    vh = *(const bfrag*)&bh[512];      vl = *(const bfrag*)&bl[512];
    MFMA3(a01, ah0, al0, vh, vl); MFMA3(a11, ah1, al1, vh, vl); MFMA3(a21, ah2, al2, vh, vl);
    vh = *(const bfrag*)&bh[1024];     vl = *(const bfrag*)&bl[1024];
    MFMA3(a02, ah0, al0, vh, vl); MFMA3(a12, ah1, al1, vh, vl); MFMA3(a22, ah2, al2, vh, vl);
    vh = *(const bfrag*)&bh[1536];     vl = *(const bfrag*)&bl[1536];
    MFMA3(a03, ah0, al0, vh, vl); MFMA3(a13, ah1, al1, vh, vl); MFMA3(a23, ah2, al2, vh, vl);
  }

  // ---- epilogue: bias + tanh + rt weight, reduce over e, store ----
  // D: col(n)=lm, row(e)= mt*16 + lk*4 + r
  const float* b2k = b2 + (k + 1) * H_;
  float* aggp = agg3 + ((size_t)k * NODES + node) * H_;

  #define EPI(NT, A0, A1, A2) do {                                             \
    const int nn_ = wv * 64 + (NT) * 16 + lm;                                  \
    const float bb_ = b2k[nn_];                                                \
    float p_;                                                                  \
    p_  = rt_l[lk * 4 + 0] * fast_tanh(A0[0] + bb_);                           \
    p_ += rt_l[lk * 4 + 1] * fast_tanh(A0[1] + bb_);                           \
    p_ += rt_l[lk * 4 + 2] * fast_tanh(A0[2] + bb_);                           \
    p_ += rt_l[lk * 4 + 3] * fast_tanh(A0[3] + bb_);                           \
    p_ += rt_l[16 + lk * 4 + 0] * fast_tanh(A1[0] + bb_);                      \
    p_ += rt_l[16 + lk * 4 + 1] * fast_tanh(A1[1] + bb_);                      \
    p_ += rt_l[16 + lk * 4 + 2] * fast_tanh(A1[2] + bb_);                      \
    p_ += rt_l[16 + lk * 4 + 3] * fast_tanh(A1[3] + bb_);                      \
    p_ += rt_l[32 + lk * 4 + 0] * fast_tanh(A2[0] + bb_);                      \
    p_ += rt_l[32 + lk * 4 + 1] * fast_tanh(A2[1] + bb_);                      \
    p_ += rt_l[32 + lk * 4 + 2] * fast_tanh(A2[2] + bb_);                      \
    p_ += rt_l[32 + lk * 4 + 3] * fast_tanh(A2[3] + bb_);                      \
    p_ += __shfl_xor(p_, 16);                                                  \
    p_ += __shfl_xor(p_, 32);                                                  \
    if (lk == 0) aggp[nn_] = p_ * (1.0f / 12.0f);                              \
  } while (0)

  EPI(0, a00, a10, a20);
  EPI(1, a01, a11, a21);
  EPI(2, a02, a12, a22);
  EPI(3, a03, a13, a23);
}

// ---------------- gru: hidden update (unchanged) ---------------------------
__global__ __launch_bounds__(256, 4) void gru_kernel(
    const float* __restrict__ hprev, const float* __restrict__ agg3,
    const float* __restrict__ data,
    const float* __restrict__ wr, const float* __restrict__ wi, const float* __restrict__ wn,
    const float* __restrict__ xrw, const float* __restrict__ xrb,
    const float* __restrict__ xiw, const float* __restrict__ xib,
    const float* __restrict__ xnw, const float* __restrict__ xnb,
    float* __restrict__ hout, int t) {
  const int node0 = (blockIdx.x >> 1) * 2;
  const int half  = blockIdx.x & 1;
  __shared__ float al[256][2];
  for (int i = threadIdx.x; i < 2 * 256; i += 256) {
    int nd = i >> 8, f = i & 255;
    size_t off = (size_t)(node0 + nd) * H_ + f;
    al[f][nd] = agg3[off] + agg3[(size_t)NODES * H_ + off] + agg3[2 * (size_t)NODES * H_ + off];
  }
  __syncthreads();
  const int hh = threadIdx.x & 127;
  const int h = half * 128 + hh;
  const int u = threadIdx.x >> 7;
  float ar = 0, ai = 0, an = 0;
  const float* pr = wr + h;
  const float* pi = wi + h;
  const float* pn = wn + h;
  for (int f0 = 0; f0 < 256; f0 += 8) {
    float wrv[8], wiv[8], wnv[8];
    #pragma unroll
    for (int j = 0; j < 8; ++j) {
      wrv[j] = pr[(f0 + j) * H_];
      wiv[j] = pi[(f0 + j) * H_];
      wnv[j] = pn[(f0 + j) * H_];
    }
    #pragma unroll
    for (int j = 0; j < 8; ++j) {
      float a = al[f0 + j][u];
      ar = fmaf(a, wrv[j], ar);
      ai = fmaf(a, wiv[j], ai);
      an = fmaf(a, wnv[j], an);
    }
  }
  {
    int node = node0 + u;
    const float* ins = data + (size_t)(node * 10 + t) * 4;
    float xr = xrb[h], xi = xib[h], xn = xnb[h];
    #pragma unroll
    for (int dd = 0; dd < 4; ++dd) {
      float iv = ins[dd];
      xr = fmaf(iv, xrw[dd * H_ + h], xr);
      xi = fmaf(iv, xiw[dd * H_ + h], xi);
      xn = fmaf(iv, xnw[dd * H_ + h], xn);
    }
    float r  = fast_sigmoid(xr + ar);
    float ii = fast_sigmoid(xi + ai);
    float ng = fast_tanh(xn + r * an);
    float hp = hprev[node * H_ + h];
    hout[node * H_ + h] = (1.0f - ii) * ng + ii * hp;
  }
}

// ---------------- pred: batched output MLP + residual (unchanged) ----------
__global__ __launch_bounds__(256) void pred_kernel(
    const float* __restrict__ h_all, const float* __restrict__ data,
    const float* __restrict__ o1w, const float* __restrict__ o1b,
    const float* __restrict__ o2w, const float* __restrict__ o2b,
    const float* __restrict__ o3w, const float* __restrict__ o3b,
    float* __restrict__ out) {
  const int row0 = blockIdx.x * 16;
  const int tid = threadIdx.x;
  __shared__ float hlt[256][20];
  __shared__ float p1t[256][20];
  __shared__ float p2t[256][20];
  __shared__ float red2[16][16][4];
  for (int i = tid; i < 16 * 256; i += 256) {
    int r = i >> 8, f = i & 255;
    int row = row0 + r, t = row / NODES, nodeI = row % NODES;
    hlt[f][r] = h_all[(size_t)(t + 1) * NODES * H_ + nodeI * H_ + f];
  }
  __syncthreads();
  const int h = tid;
  float acc[16];
  #pragma unroll
  for (int r = 0; r < 16; ++r) acc[r] = 0.0f;
  #pragma unroll 2
  for (int f = 0; f < 256; ++f) {
    float w = o1w[f * H_ + h];
    const float4 g0 = *(const float4*)&hlt[f][0];
    const float4 g1 = *(const float4*)&hlt[f][4];
    const float4 g2 = *(const float4*)&hlt[f][8];
    const float4 g3 = *(const float4*)&hlt[f][12];
    float gv[16] = {g0.x,g0.y,g0.z,g0.w, g1.x,g1.y,g1.z,g1.w,
                    g2.x,g2.y,g2.z,g2.w, g3.x,g3.y,g3.z,g3.w};
    #pragma unroll
    for (int r = 0; r < 16; ++r) acc[r] = fmaf(gv[r], w, acc[r]);
  }
  {
    float bv = o1b[h];
    #pragma unroll
    for (int r = 0; r < 16; ++r) p1t[h][r] = fmaxf(acc[r] + bv, 0.0f);
  }
  __syncthreads();
  #pragma unroll
  for (int r = 0; r < 16; ++r) acc[r] = 0.0f;
  #pragma unroll 2
  for (int f = 0; f < 256; ++f) {
    float w = o2w[f * H_ + h];
    const float4 g0 = *(const float4*)&p1t[f][0];
    const float4 g1 = *(const float4*)&p1t[f][4];
    const float4 g2 = *(const float4*)&p1t[f][8];
    const float4 g3 = *(const float4*)&p1t[f][12];
    float gv[16] = {g0.x,g0.y,g0.z,g0.w, g1.x,g1.y,g1.z,g1.w,
                    g2.x,g2.y,g2.z,g2.w, g3.x,g3.y,g3.z,g3.w};
    #pragma unroll
    for (int r = 0; r < 16; ++r) acc[r] = fmaf(gv[r], w, acc[r]);
  }
  {
    float bv = o2b[h];
    #pragma unroll
    for (int r = 0; r < 16; ++r) p2t[h][r] = fmaxf(acc[r] + bv, 0.0f);
  }
  __syncthreads();
  {
    int r = tid >> 4, p = tid & 15;
    float s0 = 0, s1 = 0, s2 = 0, s3 = 0;
    #pragma unroll
    for (int q = 0; q < 16; ++q) {
      int f = p * 16 + q;
      float v = p2t[f][r];
      s0 = fmaf(v, o3w[f * 4 + 0], s0);
      s1 = fmaf(v, o3w[f * 4 + 1], s1);
      s2 = fmaf(v, o3w[f * 4 + 2], s2);
      s3 = fmaf(v, o3w[f * 4 + 3], s3);
    }
    red2[r][p][0] = s0; red2[r][p][1] = s1; red2[r][p][2] = s2; red2[r][p][3] = s3;
  }
  __syncthreads();
  if (tid < 64) {
    int r = tid >> 2, dd = tid & 3;
    float s = o3b[dd];
    #pragma unroll
    for (int p = 0; p < 16; ++p) s += red2[r][p][dd];
    int row = row0 + r, t = row / NODES, nodeI = row % NODES;
    s += data[(size_t)(nodeI * 10 + t) * 4 + dd];
    out[(size_t)(nodeI * TS + t) * 4 + dd] = s;
  }
}

// ---------------------------------------------------------------------------
extern "C" void kernel_launch(void* const* d_in, const int* in_sizes, int n_in,
                              void* d_out, int out_size, void* d_ws, size_t ws_size,
                              hipStream_t stream) {
  const float* data     = (const float*)d_in[0];
  const float* rel_type = (const float*)d_in[1];
  const float* w1  = (const float*)d_in[4];
  const float* b1  = (const float*)d_in[5];
  const float* w2  = (const float*)d_in[6];
  const float* b2  = (const float*)d_in[7];
  const float* hr  = (const float*)d_in[8];
  const float* hi  = (const float*)d_in[9];
  const float* hn  = (const float*)d_in[10];
  const float* inr_w = (const float*)d_in[11]; const float* inr_b = (const float*)d_in[12];
  const float* ini_w = (const float*)d_in[13]; const float* ini_b = (const float*)d_in[14];
  const float* inn_w = (const float*)d_in[15]; const float* inn_b = (const float*)d_in[16];
  const float* o1w = (const float*)d_in[17]; const float* o1b = (const float*)d_in[18];
  const float* o2w = (const float*)d_in[19]; const float* o2b = (const float*)d_in[20];
  const float* o3w = (const float*)d_in[21]; const float* o3b = (const float*)d_in[22];
  float* out = (float*)d_out;

  float* ws    = (float*)d_ws;
  float* h_all = ws;                        // [10][384][256]
  float* PA    = ws + 10 * NODES * H_;      // [3][384][256]
  float* PS    = PA + 3 * NODES * H_;       // [3][384][256]
  float* agg3  = PS + 3 * NODES * H_;       // [3][384][256]
  unsigned short* W2Bhi = (unsigned short*)(agg3 + 3 * NODES * H_);  // [3*8*16][64][8]
  unsigned short* W2Blo = W2Bhi + 3 * 8 * 16 * 64 * 8;               // 196608 each

  hipMemsetAsync(h_all, 0, NODES * H_ * sizeof(float), stream);
  w2cvt_kernel<<<384, 64, 0, stream>>>(w2, W2Bhi, W2Blo);

  for (int t = 0; t < TS; ++t) {
    proj_kernel<<<576, 256, 0, stream>>>(h_all + (size_t)t * NODES * H_, w1, b1, PA, PS);
    edge_kernel<<<dim3(N_, B_, 3), 256, 0, stream>>>(PA, PS, rel_type,
                                                     W2Bhi, W2Blo, b2, agg3);
    gru_kernel<<<384, 256, 0, stream>>>(h_all + (size_t)t * NODES * H_, agg3, data,
                                        hr, hi, hn,
                                        inr_w, inr_b, ini_w, ini_b, inn_w, inn_b,
                                        h_all + (size_t)(t + 1) * NODES * H_, t);
  }
  pred_kernel<<<216, 256, 0, stream>>>(h_all, data, o1w, o1b, o2w, o2b, o3w, o3b, out);
}

// Round 13
// 630.003 us; speedup vs baseline: 2.8777x; 1.1013x over previous
//
#include <hip/hip_runtime.h>

// NRI decoder. B=8, N=48, T-1=9, D=4, H=256, edge types 1..3, E=2256.
//
// Round 12/13: replicate the validated split-bf16 MFMA pattern (round 11 edge,
// absmax 1.5e-5) onto proj and pred:
//  - wcvt (once): 11 [256,256] mats (6 w1-parts, 3 w2, o1w, o2w) -> B-fragment
//    bf16 hi/lo.
//  - projm: grid (24,6), 16-row M-tile, 96 MFMA/wave, bias into PA.
//  - pred: mlp_kernel x2 ([3456,256]@[256,256], 72 blocks, edge-shaped,
//    relu epilogue) + pred3 (wave-per-row @[256,4] + residual).
//    P1 aliases PA/PS/agg3 (884736 floats exactly), P2 aliases h_all.
//  - edge, gru unchanged (edge counters become visible in top-5).

#define H_ 256
#define N_ 48
#define B_ 8
#define NODES 384
#define TS 9

typedef __attribute__((ext_vector_type(8))) short bfrag;   // 8 bf16 (4 VGPR)
typedef __attribute__((ext_vector_type(4))) float ffrag;   // 4 f32 acc

__device__ __forceinline__ float fast_tanh(float x) {
  float e = __expf(2.0f * x);
  return 1.0f - 2.0f * __builtin_amdgcn_rcpf(1.0f + e);
}
__device__ __forceinline__ float fast_sigmoid(float x) {
  float e = __expf(-x);
  return __builtin_amdgcn_rcpf(1.0f + e);
}
__device__ __forceinline__ unsigned short f2bf(float x) {   // rne f32->bf16
  unsigned u = __float_as_uint(x);
  return (unsigned short)((u + 0x7FFF + ((u >> 16) & 1)) >> 16);
}
__device__ __forceinline__ float bf2f(unsigned short b) {
  return __uint_as_float(((unsigned)b) << 16);
}

// ---------------- wcvt: 11 [256,256] mats -> bf16 hi/lo fragments (once) ---
// grid (128, 11), 64 thr. mat m: 0-5 w1 (k=m>>1, part=m&1), 6-8 w2 (k+1),
// 9 o1w, 10 o2w. blk = ks*16+nt. out[m][blk][lane][j] =
//   src[f=ks*32+(lane>>4)*8+j][h=nt*16+(lane&15)]
__global__ __launch_bounds__(64) void wcvt_kernel(
    const float* __restrict__ w1, const float* __restrict__ w2,
    const float* __restrict__ o1w, const float* __restrict__ o2w,
    unsigned short* __restrict__ Whi, unsigned short* __restrict__ Wlo) {
  const int m = blockIdx.y;
  const float* src;
  if (m < 6) {
    int k = m >> 1, part = m & 1;
    src = w1 + (size_t)((k + 1) * 512 + part * 256) * 256;
  } else if (m < 9) {
    src = w2 + (size_t)(m - 5) * 65536;
  } else if (m == 9) {
    src = o1w;
  } else {
    src = o2w;
  }
  const int blk = blockIdx.x;
  const int nt = blk & 15, ks = blk >> 4;
  const int l = threadIdx.x;
  const int h = nt * 16 + (l & 15);
  const int fb = ks * 32 + (l >> 4) * 8;
  const size_t ob = (size_t)m * 65536 + (size_t)blk * 512 + l * 8;
  #pragma unroll
  for (int j = 0; j < 8; ++j) {
    float v = src[(size_t)(fb + j) * 256 + h];
    unsigned short hi = f2bf(v);
    Whi[ob + j] = hi;
    Wlo[ob + j] = f2bf(v - bf2f(hi));
  }
}

#define MFMA3(ACC, AH, AL, BH, BL) do {                                      \
    ACC = __builtin_amdgcn_mfma_f32_16x16x32_bf16(AH, BH, ACC, 0, 0, 0);     \
    ACC = __builtin_amdgcn_mfma_f32_16x16x32_bf16(AL, BH, ACC, 0, 0, 0);     \
    ACC = __builtin_amdgcn_mfma_f32_16x16x32_bf16(AH, BL, ACC, 0, 0, 0);     \
  } while (0)

// ---------------- projm: PA/PS projections via MFMA ------------------------
// grid (24, 6) = (16-node tile, mat m=k*2+part); 256 thr = 4 waves, wave wv
// owns h-cols wv*64..+63. M=16 rows, K=256.
__global__ __launch_bounds__(256, 4) void projm_kernel(
    const float* __restrict__ hidden,
    const unsigned short* __restrict__ Whi, const unsigned short* __restrict__ Wlo,
    const float* __restrict__ b1, float* __restrict__ PA, float* __restrict__ PS) {
  const int node0 = blockIdx.x * 16;
  const int m = blockIdx.y;
  const int kk = m >> 1, part = m & 1;
  const int tid = threadIdx.x;

  __shared__ unsigned short ahi[16 * 256];
  __shared__ unsigned short alo[16 * 256];

  {
    const float* src = hidden + (size_t)node0 * H_ + tid;
    #define STP(R, Q) do {                                   \
      unsigned short hi_ = f2bf(Q);                          \
      int idx_ = (R) * 256 + (tid ^ (((R) & 7) << 3));       \
      ahi[idx_] = hi_;                                       \
      alo[idx_] = f2bf((Q) - bf2f(hi_));                     \
    } while (0)
    {
      float q0 = src[0 * 256], q1 = src[1 * 256], q2 = src[2 * 256], q3 = src[3 * 256];
      float q4 = src[4 * 256], q5 = src[5 * 256], q6 = src[6 * 256], q7 = src[7 * 256];
      STP(0, q0); STP(1, q1); STP(2, q2); STP(3, q3);
      STP(4, q4); STP(5, q5); STP(6, q6); STP(7, q7);
    }
    {
      float q0 = src[8 * 256], q1 = src[9 * 256], q2 = src[10 * 256], q3 = src[11 * 256];
      float q4 = src[12 * 256], q5 = src[13 * 256], q6 = src[14 * 256], q7 = src[15 * 256];
      STP(8, q0); STP(9, q1); STP(10, q2); STP(11, q3);
      STP(12, q4); STP(13, q5); STP(14, q6); STP(15, q7);
    }
    #undef STP
  }
  __syncthreads();

  const int lane = tid & 63;
  const int wv = tid >> 6;
  const int lm = lane & 15;
  const int lk = lane >> 4;

  ffrag c0 = {0,0,0,0}, c1 = {0,0,0,0}, c2 = {0,0,0,0}, c3 = {0,0,0,0};
  const unsigned short* Bh = Whi + (size_t)m * 65536 + (size_t)(wv * 4) * 512 + lane * 8;
  const unsigned short* Bl = Wlo + (size_t)m * 65536 + (size_t)(wv * 4) * 512 + lane * 8;

  #pragma unroll
  for (int ks = 0; ks < 8; ++ks) {
    const int colsw = (ks * 32 + lk * 8) ^ ((lm & 7) << 3);
    bfrag ah = *(const bfrag*)&ahi[lm * 256 + colsw];
    bfrag al = *(const bfrag*)&alo[lm * 256 + colsw];
    const unsigned short* bh = Bh + ks * 8192;
    const unsigned short* bl = Bl + ks * 8192;
    bfrag vh, vl;
    vh = *(const bfrag*)&bh[0];    vl = *(const bfrag*)&bl[0];    MFMA3(c0, ah, al, vh, vl);
    vh = *(const bfrag*)&bh[512];  vl = *(const bfrag*)&bl[512];  MFMA3(c1, ah, al, vh, vl);
    vh = *(const bfrag*)&bh[1024]; vl = *(const bfrag*)&bl[1024]; MFMA3(c2, ah, al, vh, vl);
    vh = *(const bfrag*)&bh[1536]; vl = *(const bfrag*)&bl[1536]; MFMA3(c3, ah, al, vh, vl);
  }

  // D: col(h)=lm, row(node)=lk*4+r
  float* dst = (part ? PS : PA) + (size_t)kk * NODES * H_;
  const float* bias1 = b1 + (kk + 1) * H_;
  #define PEPI(NT, C) do {                                               \
    const int h_ = wv * 64 + (NT) * 16 + lm;                             \
    const float bv_ = part ? 0.0f : bias1[h_];                           \
    dst[(size_t)(node0 + lk * 4 + 0) * H_ + h_] = C[0] + bv_;            \
    dst[(size_t)(node0 + lk * 4 + 1) * H_ + h_] = C[1] + bv_;            \
    dst[(size_t)(node0 + lk * 4 + 2) * H_ + h_] = C[2] + bv_;            \
    dst[(size_t)(node0 + lk * 4 + 3) * H_ + h_] = C[3] + bv_;            \
  } while (0)
  PEPI(0, c0); PEPI(1, c1); PEPI(2, c2); PEPI(3, c3);
  #undef PEPI
}

// ---------------- edge: split-bf16 MFMA GEMM + aggregate (unchanged) -------
__global__ __launch_bounds__(256, 3) void edge_kernel(
    const float* __restrict__ PA, const float* __restrict__ PS,
    const float* __restrict__ rel_type,
    const unsigned short* __restrict__ Bhi, const unsigned short* __restrict__ Blo,
    const float* __restrict__ b2, float* __restrict__ agg3) {
  const int n = blockIdx.x;
  const int b = blockIdx.y;
  const int k = blockIdx.z;
  const int tid = threadIdx.x;
  const int node = b * N_ + n;

  __shared__ unsigned short m1hi[48 * 256];
  __shared__ unsigned short m1lo[48 * 256];
  __shared__ float rt_l[48];

  if (tid < 48)
    rt_l[tid] = (tid < 47) ? rel_type[(size_t)(b * 2256 + n * 47 + tid) * 4 + (k + 1)] : 0.0f;

  {
    const float av = PA[(size_t)k * NODES * H_ + (size_t)node * H_ + tid];
    const float* PSk = PS + (size_t)k * NODES * H_ + (size_t)b * N_ * H_;

    #define STROW(E, Q) do {                                          \
      float v_ = ((E) < 47) ? fast_tanh(av + (Q)) : 0.0f;             \
      unsigned short hi_ = f2bf(v_);                                  \
      int idx_ = (E) * 256 + (tid ^ (((E) & 7) << 3));                \
      m1hi[idx_] = hi_;                                               \
      m1lo[idx_] = f2bf(v_ - bf2f(hi_));                              \
    } while (0)

    #pragma unroll
    for (int g = 0; g < 8; ++g) {
      const int j0 = g * 6;
      const int E0 = j0, E1 = j0 + 1, E2 = j0 + 2, E3 = j0 + 3, E4 = j0 + 4, E5 = j0 + 5;
      const int s0 = (E0 < 47) ? E0 + (E0 >= n) : 0;
      const int s1 = (E1 < 47) ? E1 + (E1 >= n) : 0;
      const int s2 = (E2 < 47) ? E2 + (E2 >= n) : 0;
      const int s3 = (E3 < 47) ? E3 + (E3 >= n) : 0;
      const int s4 = (E4 < 47) ? E4 + (E4 >= n) : 0;
      const int s5 = (E5 < 47) ? E5 + (E5 >= n) : 0;
      float q0 = PSk[(size_t)s0 * H_ + tid];
      float q1 = PSk[(size_t)s1 * H_ + tid];
      float q2 = PSk[(size_t)s2 * H_ + tid];
      float q3 = PSk[(size_t)s3 * H_ + tid];
      float q4 = PSk[(size_t)s4 * H_ + tid];
      float q5 = PSk[(size_t)s5 * H_ + tid];
      STROW(E0, q0); STROW(E1, q1); STROW(E2, q2);
      STROW(E3, q3); STROW(E4, q4); STROW(E5, q5);
    }
    #undef STROW
  }
  __syncthreads();

  const int lane = tid & 63;
  const int wv = tid >> 6;
  const int lm = lane & 15;
  const int lk = lane >> 4;

  ffrag a00 = {0,0,0,0}, a01 = {0,0,0,0}, a02 = {0,0,0,0}, a03 = {0,0,0,0};
  ffrag a10 = {0,0,0,0}, a11 = {0,0,0,0}, a12 = {0,0,0,0}, a13 = {0,0,0,0};
  ffrag a20 = {0,0,0,0}, a21 = {0,0,0,0}, a22 = {0,0,0,0}, a23 = {0,0,0,0};

  const unsigned short* Bh = Bhi + (size_t)k * 65536 + (size_t)(wv * 4) * 512 + lane * 8;
  const unsigned short* Bl = Blo + (size_t)k * 65536 + (size_t)(wv * 4) * 512 + lane * 8;

  #pragma unroll
  for (int ks = 0; ks < 8; ++ks) {
    const int colsw = (ks * 32 + lk * 8) ^ ((lm & 7) << 3);
    bfrag ah0 = *(const bfrag*)&m1hi[lm * 256 + colsw];
    bfrag ah1 = *(const bfrag*)&m1hi[(16 + lm) * 256 + colsw];
    bfrag ah2 = *(const bfrag*)&m1hi[(32 + lm) * 256 + colsw];
    bfrag al0 = *(const bfrag*)&m1lo[lm * 256 + colsw];
    bfrag al1 = *(const bfrag*)&m1lo[(16 + lm) * 256 + colsw];
    bfrag al2 = *(const bfrag*)&m1lo[(32 + lm) * 256 + colsw];
    const unsigned short* bh = Bh + ks * 8192;
    const unsigned short* bl = Bl + ks * 8192;
    bfrag vh, vl;
    vh = *(const bfrag*)&bh[0];        vl = *(const bfrag*)&bl[0];
    MFMA3(a00, ah0, al0, vh, vl); MFMA3(a10, ah1, al1, vh, vl); MFMA3(a20, ah2, al2, vh, vl);
    vh = *(const bfrag*)&bh[512];      vl = *(const bfrag*)&bl[512];
    MFMA3(a01, ah0, al0, vh, vl); MFMA3(a11, ah1, al1, vh, vl); MFMA3(a21, ah2, al2, vh, vl);
    vh = *(const bfrag*)&bh[1024];     vl = *(const bfrag*)&bl[1024];
    MFMA3(a02, ah0, al0, vh, vl); MFMA3(a12, ah1, al1, vh, vl); MFMA3(a22, ah2, al2, vh, vl);
    vh = *(const bfrag*)&bh[1536];     vl = *(const bfrag*)&bl[1536];
    MFMA3(a03, ah0, al0, vh, vl); MFMA3(a13, ah1, al1, vh, vl); MFMA3(a23, ah2, al2, vh, vl);
  }

  const float* b2k = b2 + (k + 1) * H_;
  float* aggp = agg3 + ((size_t)k * NODES + node) * H_;

  #define EPI(NT, A0, A1, A2) do {                                             \
    const int nn_ = wv * 64 + (NT) * 16 + lm;                                  \
    const float bb_ = b2k[nn_];                                                \
    float p_;                                                                  \
    p_  = rt_l[lk * 4 + 0] * fast_tanh(A0[0] + bb_);                           \
    p_ += rt_l[lk * 4 + 1] * fast_tanh(A0[1] + bb_);                           \
    p_ += rt_l[lk * 4 + 2] * fast_tanh(A0[2] + bb_);                           \
    p_ += rt_l[lk * 4 + 3] * fast_tanh(A0[3] + bb_);                           \
    p_ += rt_l[16 + lk * 4 + 0] * fast_tanh(A1[0] + bb_);                      \
    p_ += rt_l[16 + lk * 4 + 1] * fast_tanh(A1[1] + bb_);                      \
    p_ += rt_l[16 + lk * 4 + 2] * fast_tanh(A1[2] + bb_);                      \
    p_ += rt_l[16 + lk * 4 + 3] * fast_tanh(A1[3] + bb_);                      \
    p_ += rt_l[32 + lk * 4 + 0] * fast_tanh(A2[0] + bb_);                      \
    p_ += rt_l[32 + lk * 4 + 1] * fast_tanh(A2[1] + bb_);                      \
    p_ += rt_l[32 + lk * 4 + 2] * fast_tanh(A2[2] + bb_);                      \
    p_ += rt_l[32 + lk * 4 + 3] * fast_tanh(A2[3] + bb_);                      \
    p_ += __shfl_xor(p_, 16);                                                  \
    p_ += __shfl_xor(p_, 32);                                                  \
    if (lk == 0) aggp[nn_] = p_ * (1.0f / 12.0f);                              \
  } while (0)

  EPI(0, a00, a10, a20);
  EPI(1, a01, a11, a21);
  EPI(2, a02, a12, a22);
  EPI(3, a03, a13, a23);
  #undef EPI
}

// ---------------- mlp: [3456,256]@[256,256] + bias + relu ------------------
// grid 72 x 48 rows; edge-shaped block (3 M-tiles x 16 N-tiles / 4 waves).
__global__ __launch_bounds__(256, 3) void mlp_kernel(
    const float* __restrict__ A,
    const unsigned short* __restrict__ Bhi, const unsigned short* __restrict__ Blo,
    const float* __restrict__ bias, float* __restrict__ out) {
  const int row0 = blockIdx.x * 48;
  const int tid = threadIdx.x;

  __shared__ unsigned short ahi[48 * 256];
  __shared__ unsigned short alo[48 * 256];

  {
    const float* src = A + (size_t)row0 * 256 + tid;
    #define STW(R, Q) do {                                   \
      unsigned short hi_ = f2bf(Q);                          \
      int idx_ = (R) * 256 + (tid ^ (((R) & 7) << 3));       \
      ahi[idx_] = hi_;                                       \
      alo[idx_] = f2bf((Q) - bf2f(hi_));                     \
    } while (0)
    #pragma unroll
    for (int g = 0; g < 6; ++g) {
      const int r0 = g * 8;
      float q0 = src[(size_t)(r0 + 0) * 256], q1 = src[(size_t)(r0 + 1) * 256];
      float q2 = src[(size_t)(r0 + 2) * 256], q3 = src[(size_t)(r0 + 3) * 256];
      float q4 = src[(size_t)(r0 + 4) * 256], q5 = src[(size_t)(r0 + 5) * 256];
      float q6 = src[(size_t)(r0 + 6) * 256], q7 = src[(size_t)(r0 + 7) * 256];
      STW(r0 + 0, q0); STW(r0 + 1, q1); STW(r0 + 2, q2); STW(r0 + 3, q3);
      STW(r0 + 4, q4); STW(r0 + 5, q5); STW(r0 + 6, q6); STW(r0 + 7, q7);
    }
    #undef STW
  }
  __syncthreads();

  const int lane = tid & 63;
  const int wv = tid >> 6;
  const int lm = lane & 15;
  const int lk = lane >> 4;

  ffrag a00 = {0,0,0,0}, a01 = {0,0,0,0}, a02 = {0,0,0,0}, a03 = {0,0,0,0};
  ffrag a10 = {0,0,0,0}, a11 = {0,0,0,0}, a12 = {0,0,0,0}, a13 = {0,0,0,0};
  ffrag a20 = {0,0,0,0}, a21 = {0,0,0,0}, a22 = {0,0,0,0}, a23 = {0,0,0,0};

  const unsigned short* Bh = Bhi + (size_t)(wv * 4) * 512 + lane * 8;
  const unsigned short* Bl = Blo + (size_t)(wv * 4) * 512 + lane * 8;

  #pragma unroll
  for (int ks = 0; ks < 8; ++ks) {
    const int colsw = (ks * 32 + lk * 8) ^ ((lm & 7) << 3);
    bfrag ah0 = *(const bfrag*)&ahi[lm * 256 + colsw];
    bfrag ah1 = *(const bfrag*)&ahi[(16 + lm) * 256 + colsw];
    bfrag ah2 = *(const bfrag*)&ahi[(32 + lm) * 256 + colsw];
    bfrag al0 = *(const bfrag*)&alo[lm * 256 + colsw];
    bfrag al1 = *(const bfrag*)&alo[(16 + lm) * 256 + colsw];
    bfrag al2 = *(const bfrag*)&alo[(32 + lm) * 256 + colsw];
    const unsigned short* bh = Bh + ks * 8192;
    const unsigned short* bl = Bl + ks * 8192;
    bfrag vh, vl;
    vh = *(const bfrag*)&bh[0];        vl = *(const bfrag*)&bl[0];
    MFMA3(a00, ah0, al0, vh, vl); MFMA3(a10, ah1, al1, vh, vl); MFMA3(a20, ah2, al2, vh, vl);
    vh = *(const bfrag*)&bh[512];      vl = *(const bfrag*)&bl[512];
    MFMA3(a01, ah0, al0, vh, vl); MFMA3(a11, ah1, al1, vh, vl); MFMA3(a21, ah2, al2, vh, vl);
    vh = *(const bfrag*)&bh[1024];     vl = *(const bfrag*)&bl[1024];
    MFMA3(a02, ah0, al0, vh, vl); MFMA3(a12, ah1, al1, vh, vl); MFMA3(a22, ah2, al2, vh, vl);
    vh = *(const bfrag*)&bh[1536];     vl = *(const bfrag*)&bl[1536];
    MFMA3(a03, ah0, al0, vh, vl); MFMA3(a13, ah1, al1, vh, vl); MFMA3(a23, ah2, al2, vh, vl);
  }

  // D: col(h)=lm, row = mt*16 + lk*4 + r; relu(acc + bias)
  #define MEPI(MT, NT, C) do {                                                  \
    const int h_ = wv * 64 + (NT) * 16 + lm;                                    \
    const float bv_ = bias[h_];                                                 \
    const int rbase_ = row0 + (MT) * 16 + lk * 4;                               \
    out[(size_t)(rbase_ + 0) * 256 + h_] = fmaxf(C[0] + bv_, 0.0f);             \
    out[(size_t)(rbase_ + 1) * 256 + h_] = fmaxf(C[1] + bv_, 0.0f);             \
    out[(size_t)(rbase_ + 2) * 256 + h_] = fmaxf(C[2] + bv_, 0.0f);             \
    out[(size_t)(rbase_ + 3) * 256 + h_] = fmaxf(C[3] + bv_, 0.0f);             \
  } while (0)
  MEPI(0, 0, a00); MEPI(0, 1, a01); MEPI(0, 2, a02); MEPI(0, 3, a03);
  MEPI(1, 0, a10); MEPI(1, 1, a11); MEPI(1, 2, a12); MEPI(1, 3, a13);
  MEPI(2, 0, a20); MEPI(2, 1, a21); MEPI(2, 2, a22); MEPI(2, 3, a23);
  #undef MEPI
}

// ---------------- pred3: out = data + P2 @ o3w + o3b (wave per row) --------
// grid 864, 256 thr = 4 waves; row = blk*4 + wave.
__global__ __launch_bounds__(256) void pred3_kernel(
    const float* __restrict__ P2, const float* __restrict__ data,
    const float* __restrict__ o3w, const float* __restrict__ o3b,
    float* __restrict__ out) {
  const int tid = threadIdx.x;
  const int lane = tid & 63;
  const int row = blockIdx.x * 4 + (tid >> 6);     // 0..3455 (t*384+node)
  const float4 v = *(const float4*)&P2[(size_t)row * 256 + lane * 4];
  const float4 w0 = *(const float4*)&o3w[(lane * 4 + 0) * 4];
  const float4 w1 = *(const float4*)&o3w[(lane * 4 + 1) * 4];
  const float4 w2 = *(const float4*)&o3w[(lane * 4 + 2) * 4];
  const float4 w3 = *(const float4*)&o3w[(lane * 4 + 3) * 4];
  float s0 = v.x * w0.x + v.y * w1.x + v.z * w2.x + v.w * w3.x;
  float s1 = v.x * w0.y + v.y * w1.y + v.z * w2.y + v.w * w3.y;
  float s2 = v.x * w0.z + v.y * w1.z + v.z * w2.z + v.w * w3.z;
  float s3 = v.x * w0.w + v.y * w1.w + v.z * w2.w + v.w * w3.w;
  #pragma unroll
  for (int msk = 1; msk < 64; msk <<= 1) {
    s0 += __shfl_xor(s0, msk);
    s1 += __shfl_xor(s1, msk);
    s2 += __shfl_xor(s2, msk);
    s3 += __shfl_xor(s3, msk);
  }
  if (lane == 0) {
    const int t = row / NODES, node = row % NODES;
    const float* dp = data + (size_t)(node * 10 + t) * 4;
    float* op = out + (size_t)(node * TS + t) * 4;
    op[0] = dp[0] + o3b[0] + s0;
    op[1] = dp[1] + o3b[1] + s1;
    op[2] = dp[2] + o3b[2] + s2;
    op[3] = dp[3] + o3b[3] + s3;
  }
}

// ---------------- gru: hidden update (unchanged) ---------------------------
__global__ __launch_bounds__(256, 4) void gru_kernel(
    const float* __restrict__ hprev, const float* __restrict__ agg3,
    const float* __restrict__ data,
    const float* __restrict__ wr, const float* __restrict__ wi, const float* __restrict__ wn,
    const float* __restrict__ xrw, const float* __restrict__ xrb,
    const float* __restrict__ xiw, const float* __restrict__ xib,
    const float* __restrict__ xnw, const float* __restrict__ xnb,
    float* __restrict__ hout, int t) {
  const int node0 = (blockIdx.x >> 1) * 2;
  const int half  = blockIdx.x & 1;
  __shared__ float al[256][2];
  for (int i = threadIdx.x; i < 2 * 256; i += 256) {
    int nd = i >> 8, f = i & 255;
    size_t off = (size_t)(node0 + nd) * H_ + f;
    al[f][nd] = agg3[off] + agg3[(size_t)NODES * H_ + off] + agg3[2 * (size_t)NODES * H_ + off];
  }
  __syncthreads();
  const int hh = threadIdx.x & 127;
  const int h = half * 128 + hh;
  const int u = threadIdx.x >> 7;
  float ar = 0, ai = 0, an = 0;
  const float* pr = wr + h;
  const float* pi = wi + h;
  const float* pn = wn + h;
  for (int f0 = 0; f0 < 256; f0 += 8) {
    float wrv[8], wiv[8], wnv[8];
    #pragma unroll
    for (int j = 0; j < 8; ++j) {
      wrv[j] = pr[(f0 + j) * H_];
      wiv[j] = pi[(f0 + j) * H_];
      wnv[j] = pn[(f0 + j) * H_];
    }
    #pragma unroll
    for (int j = 0; j < 8; ++j) {
      float a = al[f0 + j][u];
      ar = fmaf(a, wrv[j], ar);
      ai = fmaf(a, wiv[j], ai);
      an = fmaf(a, wnv[j], an);
    }
  }
  {
    int node = node0 + u;
    const float* ins = data + (size_t)(node * 10 + t) * 4;
    float xr = xrb[h], xi = xib[h], xn = xnb[h];
    #pragma unroll
    for (int dd = 0; dd < 4; ++dd) {
      float iv = ins[dd];
      xr = fmaf(iv, xrw[dd * H_ + h], xr);
      xi = fmaf(iv, xiw[dd * H_ + h], xi);
      xn = fmaf(iv, xnw[dd * H_ + h], xn);
    }
    float r  = fast_sigmoid(xr + ar);
    float ii = fast_sigmoid(xi + ai);
    float ng = fast_tanh(xn + r * an);
    float hp = hprev[node * H_ + h];
    hout[node * H_ + h] = (1.0f - ii) * ng + ii * hp;
  }
}

// ---------------------------------------------------------------------------
extern "C" void kernel_launch(void* const* d_in, const int* in_sizes, int n_in,
                              void* d_out, int out_size, void* d_ws, size_t ws_size,
                              hipStream_t stream) {
  const float* data     = (const float*)d_in[0];
  const float* rel_type = (const float*)d_in[1];
  const float* w1  = (const float*)d_in[4];
  const float* b1  = (const float*)d_in[5];
  const float* w2  = (const float*)d_in[6];
  const float* b2  = (const float*)d_in[7];
  const float* hr  = (const float*)d_in[8];
  const float* hi  = (const float*)d_in[9];
  const float* hn  = (const float*)d_in[10];
  const float* inr_w = (const float*)d_in[11]; const float* inr_b = (const float*)d_in[12];
  const float* ini_w = (const float*)d_in[13]; const float* ini_b = (const float*)d_in[14];
  const float* inn_w = (const float*)d_in[15]; const float* inn_b = (const float*)d_in[16];
  const float* o1w = (const float*)d_in[17]; const float* o1b = (const float*)d_in[18];
  const float* o2w = (const float*)d_in[19]; const float* o2b = (const float*)d_in[20];
  const float* o3w = (const float*)d_in[21]; const float* o3b = (const float*)d_in[22];
  float* out = (float*)d_out;

  float* ws    = (float*)d_ws;
  float* h_all = ws;                        // [10][384][256]
  float* PA    = ws + 10 * NODES * H_;      // [3][384][256]
  float* PS    = PA + 3 * NODES * H_;       // [3][384][256]
  float* agg3  = PS + 3 * NODES * H_;       // [3][384][256]
  unsigned short* Wfhi = (unsigned short*)(agg3 + 3 * NODES * H_);  // 11*65536
  unsigned short* Wflo = Wfhi + 11 * 65536;
  // pred-phase aliases (loop-dead regions):
  float* P1 = PA;      // 3456*256 = 884736 floats = PA+PS+agg3 exactly
  float* P2 = h_all;   // 3456*256 <= 10*98304

  hipMemsetAsync(h_all, 0, NODES * H_ * sizeof(float), stream);
  wcvt_kernel<<<dim3(128, 11), 64, 0, stream>>>(w1, w2, o1w, o2w, Wfhi, Wflo);

  for (int t = 0; t < TS; ++t) {
    projm_kernel<<<dim3(24, 6), 256, 0, stream>>>(
        h_all + (size_t)t * NODES * H_, Wfhi, Wflo, b1, PA, PS);
    edge_kernel<<<dim3(N_, B_, 3), 256, 0, stream>>>(
        PA, PS, rel_type, Wfhi + 6 * 65536, Wflo + 6 * 65536, b2, agg3);
    gru_kernel<<<384, 256, 0, stream>>>(h_all + (size_t)t * NODES * H_, agg3, data,
                                        hr, hi, hn,
                                        inr_w, inr_b, ini_w, ini_b, inn_w, inn_b,
                                        h_all + (size_t)(t + 1) * NODES * H_, t);
  }
  // pred: rows [3456,256] = h_all slices 1..9 (contiguous)
  mlp_kernel<<<72, 256, 0, stream>>>(h_all + NODES * H_,
                                     Wfhi + 9 * 65536, Wflo + 9 * 65536, o1b, P1);
  mlp_kernel<<<72, 256, 0, stream>>>(P1,
                                     Wfhi + 10 * 65536, Wflo + 10 * 65536, o2b, P2);
  pred3_kernel<<<864, 256, 0, stream>>>(P2, data, o3w, o3b, out);
}